// Round 1
// baseline (86.471 us; speedup 1.0000x reference)
//
#include <hip/hip_runtime.h>

#define WPB 4  // waves (batch elements) per block

__device__ __forceinline__ float2 shflx2(float2 v, int m) {
  float2 r; r.x = __shfl_xor(v.x, m); r.y = __shfl_xor(v.y, m); return r;
}

// 2x2 complex gate on an in-register amplitude pair (a = |0>, b = |1> on this wire)
__device__ __forceinline__ void gate_pair(float2& a, float2& b, const float2* U) {
  float2 t0, t1;
  t0.x = U[0].x*a.x - U[0].y*a.y + U[1].x*b.x - U[1].y*b.y;
  t0.y = U[0].x*a.y + U[0].y*a.x + U[1].x*b.y + U[1].y*b.x;
  t1.x = U[2].x*a.x - U[2].y*a.y + U[3].x*b.x - U[3].y*b.y;
  t1.y = U[2].x*a.y + U[2].y*a.x + U[3].x*b.y + U[3].y*b.x;
  a = t0; b = t1;
}

// 2x2 complex gate where the pair partner lives in another lane (lane ^ mask)
__device__ __forceinline__ void gate_lane(float2& a, int mask, float2 cA, float2 cP) {
  float2 p = shflx2(a, mask);
  float2 t;
  t.x = cA.x*a.x - cA.y*a.y + cP.x*p.x - cP.y*p.y;
  t.y = cA.x*a.y + cA.y*a.x + cP.x*p.y + cP.y*p.x;
  a = t;
}

// wire i acts on state bit (7 - i); bits 7,6 = register index, bits 5..0 = lane
__device__ __forceinline__ void apply_gate(float2& A0, float2& A1, float2& A2, float2& A3,
                                           int wire, const float2* U, int lane) {
  if (wire == 0)      { gate_pair(A0, A2, U); gate_pair(A1, A3, U); }   // bit7 = reg bit1
  else if (wire == 1) { gate_pair(A0, A1, U); gate_pair(A2, A3, U); }   // bit6 = reg bit0
  else {
    int mask = 1 << (7 - wire);
    bool hi = (lane & mask) != 0;
    float2 cA = hi ? U[3] : U[0];
    float2 cP = hi ? U[2] : U[1];
    gate_lane(A0, mask, cA, cP);
    gate_lane(A1, mask, cA, cP);
    gate_lane(A2, mask, cA, cP);
    gate_lane(A3, mask, cA, cP);
  }
}

// Precompute the 24 batch-invariant Rot(phi,theta,omega) = RZ(w)RY(t)RZ(p) unitaries.
__global__ void prep_rot_kernel(const float* __restrict__ qw, float* __restrict__ U) {
  int t = threadIdx.x;
  if (t < 24) {
    float phi = qw[t*3+0], theta = qw[t*3+1], omega = qw[t*3+2];
    float st, ct; sincosf(0.5f*theta, &st, &ct);
    float sa, ca; sincosf(0.5f*(phi+omega), &sa, &ca);
    float sd, cd; sincosf(0.5f*(phi-omega), &sd, &cd);
    float* o = U + t*8;
    o[0] =  ct*ca; o[1] = -ct*sa;   // U00 = cos(t/2) e^{-i(p+w)/2}
    o[2] = -st*cd; o[3] = -st*sd;   // U01 = -sin(t/2) e^{+i(p-w)/2}
    o[4] =  st*cd; o[5] = -st*sd;   // U10 =  sin(t/2) e^{-i(p-w)/2}
    o[6] =  ct*ca; o[7] =  ct*sa;   // U11 = cos(t/2) e^{+i(p+w)/2}
  }
}

__global__ __launch_bounds__(64*WPB) void qblock_kernel(
    const float* __restrict__ x,  const float* __restrict__ W1, const float* __restrict__ b1,
    const float* __restrict__ W2, const float* __restrict__ b2,
    const float* __restrict__ W3, const float* __restrict__ b3,
    const float* __restrict__ Urot, const float* __restrict__ Wp, const float* __restrict__ bp,
    float* __restrict__ out, int B)
{
  __shared__ float  h1s[WPB][64];
  __shared__ float  h2s[WPB][32];
  __shared__ float2 cs [WPB][16];   // (cos(a/2), sin(a/2)) for the 16 angles

  const int lane = threadIdx.x & 63;
  const int wv   = threadIdx.x >> 6;
  int bb = blockIdx.x * WPB + wv;
  if (bb >= B) bb = B - 1;                       // duplicate work, same values
  const int b = __builtin_amdgcn_readfirstlane(bb);

  // ---- MLP layer 1: 80 -> 64, one output per lane; x row via scalar loads ----
  {
    const float4* xv = (const float4*)(x + (size_t)b * 80);
    const float4* wr = (const float4*)(W1 + lane * 80);
    float acc = b1[lane];
    #pragma unroll
    for (int k = 0; k < 20; ++k) {
      float4 xk = xv[k], wk = wr[k];
      acc = fmaf(xk.x, wk.x, acc); acc = fmaf(xk.y, wk.y, acc);
      acc = fmaf(xk.z, wk.z, acc); acc = fmaf(xk.w, wk.w, acc);
    }
    h1s[wv][lane] = tanhf(acc);
  }
  __syncthreads();

  // ---- layer 2: 64 -> 32 ----
  if (lane < 32) {
    const float4* hv = (const float4*)(&h1s[wv][0]);
    const float4* wr = (const float4*)(W2 + lane * 64);
    float acc = b2[lane];
    #pragma unroll
    for (int k = 0; k < 16; ++k) {
      float4 hk = hv[k], wk = wr[k];
      acc = fmaf(hk.x, wk.x, acc); acc = fmaf(hk.y, wk.y, acc);
      acc = fmaf(hk.z, wk.z, acc); acc = fmaf(hk.w, wk.w, acc);
    }
    h2s[wv][lane] = tanhf(acc);
  }
  __syncthreads();

  // ---- layer 3: 32 -> 16 angles; store sincos(angle/2) ----
  if (lane < 16) {
    const float4* hv = (const float4*)(&h2s[wv][0]);
    const float4* wr = (const float4*)(W3 + lane * 32);
    float acc = b3[lane];
    #pragma unroll
    for (int k = 0; k < 8; ++k) {
      float4 hk = hv[k], wk = wr[k];
      acc = fmaf(hk.x, wk.x, acc); acc = fmaf(hk.y, wk.y, acc);
      acc = fmaf(hk.z, wk.z, acc); acc = fmaf(hk.w, wk.w, acc);
    }
    float sh, ch; sincosf(0.5f * acc, &sh, &ch);
    cs[wv][lane] = make_float2(ch, sh);
  }
  __syncthreads();

  // ---- quantum state: 256 amps = 4 float2 per lane, n = reg*64 + lane ----
  float2 A0 = make_float2(0.f, 0.f), A1 = A0, A2 = A0, A3 = A0;
  if (lane == 0) A0.x = 1.f;

  // initial layer: fused U = RZ(a[i+8]) @ RY(a[i]) per qubit i
  #pragma unroll
  for (int i = 0; i < 8; ++i) {
    float2 y = cs[wv][i];       // (cy, sy)
    float2 z = cs[wv][i + 8];   // (cz, sz); e^{-i th/2} = (cz, -sz)
    float2 U[4];
    U[0] = make_float2( y.x * z.x, -y.x * z.y);
    U[1] = make_float2(-y.y * z.x,  y.y * z.y);
    U[2] = make_float2( y.y * z.x,  y.y * z.y);
    U[3] = make_float2( y.x * z.x,  y.x * z.y);
    apply_gate(A0, A1, A2, A3, i, U, lane);
  }

  // 3 entangling layers
  for (int l = 0; l < 3; ++l) {
    const float2* Ub = (const float2*)Urot + l * 32;   // 8 gates x 4 complex entries
    #pragma unroll
    for (int i = 0; i < 8; ++i) {
      float2 U[4] = { Ub[i*4+0], Ub[i*4+1], Ub[i*4+2], Ub[i*4+3] };
      apply_gate(A0, A1, A2, A3, i, U, lane);
    }
    // CNOT ring: (0,1),(1,2),...,(6,7),(7,0)
    { float2 t = A2; A2 = A3; A3 = t; }                 // (0,1): ctrl reg bit1, tgt reg bit0
    A1 = shflx2(A1, 32); A3 = shflx2(A3, 32);           // (1,2): ctrl reg bit0, tgt lane bit5
    #define CNOT_LL(cm, tm) { \
      bool c = (lane & (cm)) != 0; float2 p; \
      p = shflx2(A0, (tm)); A0 = c ? p : A0; \
      p = shflx2(A1, (tm)); A1 = c ? p : A1; \
      p = shflx2(A2, (tm)); A2 = c ? p : A2; \
      p = shflx2(A3, (tm)); A3 = c ? p : A3; }
    CNOT_LL(32, 16)   // (2,3)
    CNOT_LL(16,  8)   // (3,4)
    CNOT_LL( 8,  4)   // (4,5)
    CNOT_LL( 4,  2)   // (5,6)
    CNOT_LL( 2,  1)   // (6,7)
    { bool c = (lane & 1) != 0;                         // (7,0): ctrl lane bit0, tgt reg bit1
      float2 t0 = A0, t1 = A1;
      A0 = c ? A2 : A0; A2 = c ? t0 : A2;
      A1 = c ? A3 : A1; A3 = c ? t1 : A3; }
  }

  // ---- <Z_i> readout ----
  float p0 = A0.x*A0.x + A0.y*A0.y;
  float p1 = A1.x*A1.x + A1.y*A1.y;
  float p2 = A2.x*A2.x + A2.y*A2.y;
  float p3 = A3.x*A3.x + A3.y*A3.y;
  float s = p0 + p1 + p2 + p3;
  float zp[8];
  zp[0] = (p0 + p1) - (p2 + p3);    // wire0: state bit7 = reg bit1
  zp[1] = (p0 + p2) - (p1 + p3);    // wire1: state bit6 = reg bit0
  #pragma unroll
  for (int w = 2; w < 8; ++w) {
    int m = 1 << (7 - w);
    zp[w] = (lane & m) ? -s : s;
  }
  #pragma unroll
  for (int m = 1; m < 64; m <<= 1) {
    #pragma unroll
    for (int w = 0; w < 8; ++w) zp[w] += __shfl_xor(zp[w], m);
  }

  // ---- output projection: rows 2*lane, 2*lane+1 of Wp (128x8) ----
  const int r0 = 2 * lane;
  const float4* wp = (const float4*)(Wp + r0 * 8);   // 16 floats = rows r0, r0+1
  float4 a0 = wp[0], a1 = wp[1], c0 = wp[2], c1 = wp[3];
  float o0 = bp[r0], o1 = bp[r0 + 1];
  o0 += zp[0]*a0.x + zp[1]*a0.y + zp[2]*a0.z + zp[3]*a0.w
      + zp[4]*a1.x + zp[5]*a1.y + zp[6]*a1.z + zp[7]*a1.w;
  o1 += zp[0]*c0.x + zp[1]*c0.y + zp[2]*c0.z + zp[3]*c0.w
      + zp[4]*c1.x + zp[5]*c1.y + zp[6]*c1.z + zp[7]*c1.w;
  float2* op = (float2*)(out + (size_t)b * 128);
  op[lane] = make_float2(o0, o1);
}

extern "C" void kernel_launch(void* const* d_in, const int* in_sizes, int n_in,
                              void* d_out, int out_size, void* d_ws, size_t ws_size,
                              hipStream_t stream) {
  const float* x  = (const float*)d_in[0];
  const float* W1 = (const float*)d_in[1];
  const float* b1 = (const float*)d_in[2];
  const float* W2 = (const float*)d_in[3];
  const float* b2 = (const float*)d_in[4];
  const float* W3 = (const float*)d_in[5];
  const float* b3 = (const float*)d_in[6];
  const float* qw = (const float*)d_in[7];
  const float* Wp = (const float*)d_in[8];
  const float* bp = (const float*)d_in[9];
  float* out = (float*)d_out;
  float* Urot = (float*)d_ws;   // 24 gates x 8 floats = 768 B

  const int B = in_sizes[0] / 80;
  prep_rot_kernel<<<1, 64, 0, stream>>>(qw, Urot);
  const int grid = (B + WPB - 1) / WPB;
  qblock_kernel<<<grid, 64 * WPB, 0, stream>>>(x, W1, b1, W2, b2, W3, b3,
                                               Urot, Wp, bp, out, B);
}

// Round 2
// 61.358 us; speedup vs baseline: 1.4093x; 1.4093x over previous
//
#include <hip/hip_runtime.h>

typedef float v2f __attribute__((ext_vector_type(2)));

#define WPB 4  // waves (batch elements) per block

__device__ __forceinline__ float xorf(float v, int sb) {
  return __int_as_float(__float_as_int(v) ^ sb);
}
__device__ __forceinline__ v2f rotv(v2f v) { v2f r; r.x = -v.y; r.y = v.x; return r; }

// cross-lane xor exchange: ds_swizzle (imm pattern) for m<=16, bpermute for 32
template<int M>
__device__ __forceinline__ float shx1(float v, int a32) {
  if constexpr (M == 32)
    return __int_as_float(__builtin_amdgcn_ds_bpermute(a32, __float_as_int(v)));
  else
    return __int_as_float(__builtin_amdgcn_ds_swizzle(__float_as_int(v), (M << 10) | 0x1f));
}
template<int M>
__device__ __forceinline__ v2f shx2(v2f v, int a32) {
  v2f r; r.x = shx1<M>(v.x, a32); r.y = shx1<M>(v.y, a32); return r;
}
__device__ __forceinline__ v2f bperm2(int addr, v2f v) {
  v2f r;
  r.x = __int_as_float(__builtin_amdgcn_ds_bpermute(addr, __float_as_int(v.x)));
  r.y = __int_as_float(__builtin_amdgcn_ds_bpermute(addr, __float_as_int(v.y)));
  return r;
}

// full 2x2 Rot-structured gate on a register-local pair:
// U00=(A,Bc) U01=(C,D) U10=(-C,D) U11=(A,-Bc)
__device__ __forceinline__ void gpair(v2f& a, v2f& b, float A, float Bc, float C, float D) {
  v2f ra = rotv(a), rb = rotv(b);
  v2f na = A*a + Bc*ra + C*b + D*rb;
  v2f nb = A*b - Bc*rb - C*a + D*ra;
  a = na; b = nb;
}

// wire W on state: reg bits = wires 0,1; lane bit (5-(W-2)) = wire W for W>=2
template<int W>
__device__ __forceinline__ void gate_wire(v2f& A0, v2f& A1, v2f& A2, v2f& A3,
    float A, float Bc, float C, float D, const int* sb, int a32) {
  if constexpr (W == 0)      { gpair(A0, A2, A, Bc, C, D); gpair(A1, A3, A, Bc, C, D); }
  else if constexpr (W == 1) { gpair(A0, A1, A, Bc, C, D); gpair(A2, A3, A, Bc, C, D); }
  else {
    constexpr int M = 1 << (7 - W);
    const int s = sb[W - 2];
    float cAy = xorf(Bc, s), cPx = xorf(C, s);   // hi lane: conj/neg-conj columns
    v2f p0 = shx2<M>(A0, a32), p1 = shx2<M>(A1, a32),
        p2 = shx2<M>(A2, a32), p3 = shx2<M>(A3, a32);
    A0 = A*A0 + cAy*rotv(A0) + cPx*p0 + D*rotv(p0);
    A1 = A*A1 + cAy*rotv(A1) + cPx*p1 + D*rotv(p1);
    A2 = A*A2 + cAy*rotv(A2) + cPx*p2 + D*rotv(p2);
    A3 = A*A3 + cAy*rotv(A3) + cPx*p3 + D*rotv(p3);
  }
}

__device__ __forceinline__ float fast_tanh(float x) {
  float e = __expf(2.f * x);
  return 1.f - 2.f * __builtin_amdgcn_rcpf(e + 1.f);
}

// Precompute 24 batch-invariant Rot gates as (A,Bc,C,D) = (U00.re,U00.im,U01.re,U01.im)
__global__ void prep_rot_kernel(const float* __restrict__ qw, float* __restrict__ U) {
  int t = threadIdx.x;
  if (t < 24) {
    float phi = qw[t*3+0], theta = qw[t*3+1], omega = qw[t*3+2];
    float st, ct; sincosf(0.5f*theta, &st, &ct);
    float sa, ca; sincosf(0.5f*(phi+omega), &sa, &ca);
    float sd, cd; sincosf(0.5f*(phi-omega), &sd, &cd);
    float4 o; o.x = ct*ca; o.y = -ct*sa; o.z = -st*cd; o.w = -st*sd;
    ((float4*)U)[t] = o;
  }
}

__global__ __launch_bounds__(64*WPB) void qblock_kernel(
    const float* __restrict__ x,  const float* __restrict__ W1, const float* __restrict__ b1,
    const float* __restrict__ W2, const float* __restrict__ b2,
    const float* __restrict__ W3, const float* __restrict__ b3,
    const float* __restrict__ Urot, const float* __restrict__ Wp, const float* __restrict__ bp,
    float* __restrict__ out, int B)
{
  __shared__ float h1s[WPB][64];
  __shared__ float h2s[WPB][32];
  __shared__ v2f   cs [WPB][16];

  const int lane = threadIdx.x & 63;
  const int wv   = threadIdx.x >> 6;
  int bb = blockIdx.x * WPB + wv;
  if (bb >= B) bb = B - 1;
  const int b = __builtin_amdgcn_readfirstlane(bb);

  // ---- MLP layer 1: 80 -> 64 ----
  {
    const float4* xv = (const float4*)(x + (size_t)b * 80);
    const float4* wr = (const float4*)(W1 + lane * 80);
    float acc = b1[lane];
    #pragma unroll
    for (int k = 0; k < 20; ++k) {
      float4 xk = xv[k], wk = wr[k];
      acc = fmaf(xk.x, wk.x, acc); acc = fmaf(xk.y, wk.y, acc);
      acc = fmaf(xk.z, wk.z, acc); acc = fmaf(xk.w, wk.w, acc);
    }
    h1s[wv][lane] = fast_tanh(acc);
  }
  __threadfence_block();   // wave-local LDS ordering (no cross-wave sharing)

  // ---- layer 2: 64 -> 32 ----
  if (lane < 32) {
    const float4* hv = (const float4*)(&h1s[wv][0]);
    const float4* wr = (const float4*)(W2 + lane * 64);
    float acc = b2[lane];
    #pragma unroll
    for (int k = 0; k < 16; ++k) {
      float4 hk = hv[k], wk = wr[k];
      acc = fmaf(hk.x, wk.x, acc); acc = fmaf(hk.y, wk.y, acc);
      acc = fmaf(hk.z, wk.z, acc); acc = fmaf(hk.w, wk.w, acc);
    }
    h2s[wv][lane] = fast_tanh(acc);
  }
  __threadfence_block();

  // ---- layer 3: 32 -> 16 angles ----
  if (lane < 16) {
    const float4* hv = (const float4*)(&h2s[wv][0]);
    const float4* wr = (const float4*)(W3 + lane * 32);
    float acc = b3[lane];
    #pragma unroll
    for (int k = 0; k < 8; ++k) {
      float4 hk = hv[k], wk = wr[k];
      acc = fmaf(hk.x, wk.x, acc); acc = fmaf(hk.y, wk.y, acc);
      acc = fmaf(hk.z, wk.z, acc); acc = fmaf(hk.w, wk.w, acc);
    }
    float sh, ch; __sincosf(0.5f * acc, &sh, &ch);
    cs[wv][lane] = (v2f){ch, sh};
  }
  __threadfence_block();

  // ---- per-lane constants ----
  const int a32 = (lane ^ 32) << 2;
  const int sb[6] = { (lane&32)<<26, (lane&16)<<27, (lane&8)<<28,
                      (lane&4)<<29, (lane&2)<<30, (lane&1)<<31 };
  const int addrA = ((lane ^ (lane >> 1)) & 63) << 2;  // inverse of CNOT chain (2,3)..(6,7)
  const int addrB = addrA ^ 128;                       // + (1,2) fold for odd-reg registers

  // ---- state: 256 amps = 4 v2f per lane; n = reg*64 + lane; wire i = bit (7-i) ----
  v2f A0 = {0.f, 0.f}, A1 = A0, A2 = A0, A3 = A0;
  if (lane == 0) A0.x = 1.f;

  // initial layer: fused U = RZ(a[i+8]) RY(a[i])
  {
    #define IGATE(i) { v2f yy = cs[wv][i], zz = cs[wv][(i)+8]; \
      float Ac = yy.x*zz.x, Bc = -yy.x*zz.y, Cc = -yy.y*zz.x, Dc = yy.y*zz.y; \
      gate_wire<i>(A0,A1,A2,A3,Ac,Bc,Cc,Dc,sb,a32); }
    IGATE(0) IGATE(1) IGATE(2) IGATE(3) IGATE(4) IGATE(5) IGATE(6) IGATE(7)
    #undef IGATE
  }

  // 3 entangling layers; rings 0,1 explicit (folded bpermute), ring 2 folded into readout
  const float4* Ug = (const float4*)Urot;
  #pragma unroll
  for (int l = 0; l < 3; ++l) {
    #define LGATE(i) { float4 u = Ug[l*8+(i)]; \
      gate_wire<i>(A0,A1,A2,A3,u.x,u.y,u.z,u.w,sb,a32); }
    LGATE(0) LGATE(1) LGATE(2) LGATE(3) LGATE(4) LGATE(5) LGATE(6) LGATE(7)
    #undef LGATE
    if (l < 2) {
      { v2f t = A2; A2 = A3; A3 = t; }              // CNOT(0,1): reg rename
      A0 = bperm2(addrA, A0); A2 = bperm2(addrA, A2);
      A1 = bperm2(addrB, A1); A3 = bperm2(addrB, A3);
      bool c0 = (lane & 1) != 0;                    // CNOT(7,0)
      v2f t0 = A0, t1 = A1;
      A0 = c0 ? A2 : A0; A2 = c0 ? t0 : A2;
      A1 = c0 ? A3 : A1; A3 = c0 ? t1 : A3;
    }
  }

  // ---- readout with ring-2 folded as parity signs ----
  float p0 = A0.x*A0.x + A0.y*A0.y;
  float p1 = A1.x*A1.x + A1.y*A1.y;
  float p2 = A2.x*A2.x + A2.y*A2.y;
  float p3 = A3.x*A3.x + A3.y*A3.y;
  float E = (p0 + p3) - (p1 + p2);   // sign (w0 xor w1) over regs
  float F = (p0 + p2) - (p1 + p3);   // sign (w1) over regs
  float Fv = xorf(F, (__popc(lane) & 1) << 31);  // all-lane-bit parity

  // cascade butterfly: S = plain sum, d_k = signed over masks {32..}
  float S = E, d1, d2, d3, d4, d5, d6;
  { float p = shx1<32>(S,a32); d1 = xorf(S-p, sb[0]); S += p; }
  { float p = shx1<16>(S,a32); S += p;
    float q = shx1<16>(d1,a32); d2 = xorf(d1-q, sb[1]); d1 += q; }
  { float p = shx1<8>(S,a32);  S += p;
    float q = shx1<8>(d1,a32); d1 += q;
    float r = shx1<8>(d2,a32); d3 = xorf(d2-r, sb[2]); d2 += r; }
  { float p = shx1<4>(S,a32);  S += p;
    float q = shx1<4>(d1,a32); d1 += q;
    float r = shx1<4>(d2,a32); d2 += r;
    float t = shx1<4>(d3,a32); d4 = xorf(d3-t, sb[3]); d3 += t; }
  { float p = shx1<2>(S,a32);  S += p;
    float q = shx1<2>(d1,a32); d1 += q;
    float r = shx1<2>(d2,a32); d2 += r;
    float t = shx1<2>(d3,a32); d3 += t;
    float w = shx1<2>(d4,a32); d5 = xorf(d4-w, sb[4]); d4 += w; }
  { float p = shx1<1>(S,a32);  S += p;
    float q = shx1<1>(d1,a32); d1 += q;
    float r = shx1<1>(d2,a32); d2 += r;
    float t = shx1<1>(d3,a32); d3 += t;
    float w = shx1<1>(d4,a32); d4 += w;
    float v = shx1<1>(d5,a32); d6 = xorf(d5-v, sb[5]); d5 += v; }
  Fv += shx1<32>(Fv,a32); Fv += shx1<16>(Fv,a32); Fv += shx1<8>(Fv,a32);
  Fv += shx1<4>(Fv,a32);  Fv += shx1<2>(Fv,a32);  Fv += shx1<1>(Fv,a32);
  const float z0 = Fv, z1 = S, z2 = d1, z3 = d2, z4 = d3, z5 = d4, z6 = d5, z7 = d6;

  // ---- output projection: rows 2*lane, 2*lane+1 of Wp (128x8) ----
  const int r0 = 2 * lane;
  const float4* wp = (const float4*)(Wp + r0 * 8);
  float4 w0v = wp[0], w1v = wp[1], w2v = wp[2], w3v = wp[3];
  float2 bpv = ((const float2*)bp)[lane];
  float o0 = bpv.x + z0*w0v.x + z1*w0v.y + z2*w0v.z + z3*w0v.w
                   + z4*w1v.x + z5*w1v.y + z6*w1v.z + z7*w1v.w;
  float o1 = bpv.y + z0*w2v.x + z1*w2v.y + z2*w2v.z + z3*w2v.w
                   + z4*w3v.x + z5*w3v.y + z6*w3v.z + z7*w3v.w;
  ((float2*)(out + (size_t)b * 128))[lane] = make_float2(o0, o1);
}

extern "C" void kernel_launch(void* const* d_in, const int* in_sizes, int n_in,
                              void* d_out, int out_size, void* d_ws, size_t ws_size,
                              hipStream_t stream) {
  const float* x  = (const float*)d_in[0];
  const float* W1 = (const float*)d_in[1];
  const float* b1 = (const float*)d_in[2];
  const float* W2 = (const float*)d_in[3];
  const float* b2 = (const float*)d_in[4];
  const float* W3 = (const float*)d_in[5];
  const float* b3 = (const float*)d_in[6];
  const float* qw = (const float*)d_in[7];
  const float* Wp = (const float*)d_in[8];
  const float* bp = (const float*)d_in[9];
  float* out = (float*)d_out;
  float* Urot = (float*)d_ws;   // 24 gates x 4 floats = 384 B

  const int B = in_sizes[0] / 80;
  prep_rot_kernel<<<1, 64, 0, stream>>>(qw, Urot);
  const int grid = (B + WPB - 1) / WPB;
  qblock_kernel<<<grid, 64 * WPB, 0, stream>>>(x, W1, b1, W2, b2, W3, b3,
                                               Urot, Wp, bp, out, B);
}

// Round 3
// 61.000 us; speedup vs baseline: 1.4176x; 1.0059x over previous
//
#include <hip/hip_runtime.h>

typedef float v2f __attribute__((ext_vector_type(2)));

#define WPB 4  // waves (batch elements) per block

__device__ __forceinline__ float xorf(float v, int sb) {
  return __int_as_float(__float_as_int(v) ^ sb);
}

// ---- VOP3P packed fp32 helpers ----------------------------------------
// plain elementwise
__device__ __forceinline__ v2f pkfma(v2f a, v2f b, v2f c) {
  v2f r; asm("v_pk_fma_f32 %0, %1, %2, %3" : "=v"(r) : "v"(a), "v"(b), "v"(c)); return r;
}
// r = c.lo * v   (coefficient broadcast from lo half)
__device__ __forceinline__ v2f pkmul_bl(v2f c, v2f v) {
  v2f r; asm("v_pk_mul_f32 %0, %1, %2 op_sel:[0,0] op_sel_hi:[0,1]"
             : "=v"(r) : "v"(c), "v"(v)); return r;
}
// r = acc + c.lo * v
__device__ __forceinline__ v2f pkfma_bl(v2f c, v2f v, v2f acc) {
  v2f r; asm("v_pk_fma_f32 %0, %1, %2, %3 op_sel:[0,0,0] op_sel_hi:[0,1,1]"
             : "=v"(r) : "v"(c), "v"(v), "v"(acc)); return r;
}
// r = acc - c.lo * v
__device__ __forceinline__ v2f pkfma_bl_n(v2f c, v2f v, v2f acc) {
  v2f r; asm("v_pk_fma_f32 %0, %1, %2, %3 op_sel:[0,0,0] op_sel_hi:[0,1,1] neg_lo:[1,0,0] neg_hi:[1,0,0]"
             : "=v"(r) : "v"(c), "v"(v), "v"(acc)); return r;
}
// r = acc + i * c.hi (x) v :  r.lo = acc.lo - c.hi*v.hi ; r.hi = acc.hi + c.hi*v.lo
__device__ __forceinline__ v2f pkfma_bh_i(v2f c, v2f v, v2f acc) {
  v2f r; asm("v_pk_fma_f32 %0, %1, %2, %3 op_sel:[1,1,0] op_sel_hi:[1,0,1] neg_lo:[1,0,0]"
             : "=v"(r) : "v"(c), "v"(v), "v"(acc)); return r;
}
// r = acc - i * c.hi (x) v :  r.lo = acc.lo + c.hi*v.hi ; r.hi = acc.hi - c.hi*v.lo
__device__ __forceinline__ v2f pkfma_bh_mi(v2f c, v2f v, v2f acc) {
  v2f r; asm("v_pk_fma_f32 %0, %1, %2, %3 op_sel:[1,1,0] op_sel_hi:[1,0,1] neg_hi:[1,0,0]"
             : "=v"(r) : "v"(c), "v"(v), "v"(acc)); return r;
}

// ---- cross-lane xor exchange ------------------------------------------
template<int M>
__device__ __forceinline__ float shx1(float v, int a32) {
  if constexpr (M == 32)
    return __int_as_float(__builtin_amdgcn_ds_bpermute(a32, __float_as_int(v)));
  else
    return __int_as_float(__builtin_amdgcn_ds_swizzle(__float_as_int(v), (M << 10) | 0x1f));
}
template<int M>
__device__ __forceinline__ v2f shx2(v2f v, int a32) {
  v2f r; r.x = shx1<M>(v.x, a32); r.y = shx1<M>(v.y, a32); return r;
}
__device__ __forceinline__ v2f bperm2(int addr, v2f v) {
  v2f r;
  r.x = __int_as_float(__builtin_amdgcn_ds_bpermute(addr, __float_as_int(v.x)));
  r.y = __int_as_float(__builtin_amdgcn_ds_bpermute(addr, __float_as_int(v.y)));
  return r;
}

// ---- gates -------------------------------------------------------------
// Rot-structured gate, P1=(A,Bc)=U00, P2=(C,D)=U01; U10=(-C,D), U11=(A,-Bc)
__device__ __forceinline__ void gpair(v2f& a, v2f& b, v2f P1, v2f P2) {
  v2f na = pkmul_bl(P1, a);
  na = pkfma_bh_i(P1, a, na);
  na = pkfma_bl(P2, b, na);
  na = pkfma_bh_i(P2, b, na);
  v2f nb = pkmul_bl(P1, b);
  nb = pkfma_bh_mi(P1, b, nb);
  nb = pkfma_bl_n(P2, a, nb);
  nb = pkfma_bh_i(P2, a, nb);
  a = na; b = nb;
}
// lane-partner gate: this lane's row coefficients (signs pre-xored into P1.y,P2.x)
__device__ __forceinline__ v2f glane(v2f a, v2f p, v2f P1, v2f P2) {
  v2f t = pkmul_bl(P1, a);
  t = pkfma_bh_i(P1, a, t);
  t = pkfma_bl(P2, p, t);
  t = pkfma_bh_i(P2, p, t);
  return t;
}

// wire W: reg bits = wires 0,1; lane bit (7-W) = wire W for W>=2
template<int W>
__device__ __forceinline__ void gate_wire(v2f& A0, v2f& A1, v2f& A2, v2f& A3,
    v2f P1, v2f P2, const int* sb, int a32) {
  if constexpr (W == 0)      { gpair(A0, A2, P1, P2); gpair(A1, A3, P1, P2); }
  else if constexpr (W == 1) { gpair(A0, A1, P1, P2); gpair(A2, A3, P1, P2); }
  else {
    constexpr int M = 1 << (7 - W);
    const int s = sb[W - 2];
    P1.y = xorf(P1.y, s);   // hi lanes: conj column
    P2.x = xorf(P2.x, s);
    v2f p0 = shx2<M>(A0, a32), p1 = shx2<M>(A1, a32),
        p2 = shx2<M>(A2, a32), p3 = shx2<M>(A3, a32);
    A0 = glane(A0, p0, P1, P2);
    A1 = glane(A1, p1, P1, P2);
    A2 = glane(A2, p2, P1, P2);
    A3 = glane(A3, p3, P1, P2);
  }
}

__device__ __forceinline__ float fast_tanh(float x) {
  float e = __expf(2.f * x);
  return 1.f - 2.f * __builtin_amdgcn_rcpf(e + 1.f);
}
__device__ __forceinline__ v2f vlo(float4 v) { return (v2f){v.x, v.y}; }
__device__ __forceinline__ v2f vhi(float4 v) { return (v2f){v.z, v.w}; }

// Precompute 24 batch-invariant Rot gates as (A,Bc,C,D)
__global__ void prep_rot_kernel(const float* __restrict__ qw, float* __restrict__ U) {
  int t = threadIdx.x;
  if (t < 24) {
    float phi = qw[t*3+0], theta = qw[t*3+1], omega = qw[t*3+2];
    float st, ct; sincosf(0.5f*theta, &st, &ct);
    float sa, ca; sincosf(0.5f*(phi+omega), &sa, &ca);
    float sd, cd; sincosf(0.5f*(phi-omega), &sd, &cd);
    float4 o; o.x = ct*ca; o.y = -ct*sa; o.z = -st*cd; o.w = -st*sd;
    ((float4*)U)[t] = o;
  }
}

__global__ __launch_bounds__(64*WPB) void qblock_kernel(
    const float* __restrict__ x,  const float* __restrict__ W1, const float* __restrict__ b1,
    const float* __restrict__ W2, const float* __restrict__ b2,
    const float* __restrict__ W3, const float* __restrict__ b3,
    const float* __restrict__ Urot, const float* __restrict__ Wp, const float* __restrict__ bp,
    float* __restrict__ out, int B)
{
  __shared__ float h1s[WPB][64];
  __shared__ float h2s[WPB][32];
  __shared__ v2f   cs [WPB][16];

  const int lane = threadIdx.x & 63;
  const int wv   = threadIdx.x >> 6;
  int bb = blockIdx.x * WPB + wv;
  if (bb >= B) bb = B - 1;
  const int b = __builtin_amdgcn_readfirstlane(bb);

  // ---- MLP layer 1: 80 -> 64 (pk-packed dot) ----
  {
    const float4* xv = (const float4*)(x + (size_t)b * 80);
    const float4* wr = (const float4*)(W1 + lane * 80);
    v2f ac0 = (v2f){b1[lane], 0.f}, ac1 = (v2f){0.f, 0.f};
    #pragma unroll
    for (int k = 0; k < 20; ++k) {
      float4 xk = xv[k], wk = wr[k];
      ac0 = pkfma(vlo(xk), vlo(wk), ac0);
      ac1 = pkfma(vhi(xk), vhi(wk), ac1);
    }
    h1s[wv][lane] = fast_tanh((ac0.x + ac0.y) + (ac1.x + ac1.y));
  }
  __threadfence_block();

  // ---- layer 2: 64 -> 32 ----
  if (lane < 32) {
    const float4* hv = (const float4*)(&h1s[wv][0]);
    const float4* wr = (const float4*)(W2 + lane * 64);
    v2f ac0 = (v2f){b2[lane], 0.f}, ac1 = (v2f){0.f, 0.f};
    #pragma unroll
    for (int k = 0; k < 16; ++k) {
      float4 hk = hv[k], wk = wr[k];
      ac0 = pkfma(vlo(hk), vlo(wk), ac0);
      ac1 = pkfma(vhi(hk), vhi(wk), ac1);
    }
    h2s[wv][lane] = fast_tanh((ac0.x + ac0.y) + (ac1.x + ac1.y));
  }
  __threadfence_block();

  // ---- layer 3: 32 -> 16 angles ----
  if (lane < 16) {
    const float4* hv = (const float4*)(&h2s[wv][0]);
    const float4* wr = (const float4*)(W3 + lane * 32);
    v2f ac0 = (v2f){b3[lane], 0.f}, ac1 = (v2f){0.f, 0.f};
    #pragma unroll
    for (int k = 0; k < 8; ++k) {
      float4 hk = hv[k], wk = wr[k];
      ac0 = pkfma(vlo(hk), vlo(wk), ac0);
      ac1 = pkfma(vhi(hk), vhi(wk), ac1);
    }
    float sh, ch; __sincosf(0.5f * ((ac0.x + ac0.y) + (ac1.x + ac1.y)), &sh, &ch);
    cs[wv][lane] = (v2f){ch, sh};
  }
  __threadfence_block();

  // ---- per-lane constants ----
  const int a32 = (lane ^ 32) << 2;
  const int sb[6] = { (lane&32)<<26, (lane&16)<<27, (lane&8)<<28,
                      (lane&4)<<29, (lane&2)<<30, (lane&1)<<31 };
  const int addrA = ((lane ^ (lane >> 1)) & 63) << 2;  // inverse of CNOT chain (2,3)..(6,7)
  const int addrB = addrA ^ 128;                       // + (1,2) fold for odd-reg registers

  // ---- state: 256 amps = 4 v2f per lane; n = reg*64 + lane; wire i = bit (7-i) ----
  v2f A0 = (v2f){0.f, 0.f}, A1 = A0, A2 = A0, A3 = A0;
  if (lane == 0) A0.x = 1.f;

  // initial layer: fused U = RZ(a[i+8]) RY(a[i]):  A=cy*cz, Bc=-cy*sz, C=-sy*cz, D=sy*sz
  {
    #define IGATE(i) { v2f yy = cs[wv][i], zz = cs[wv][(i)+8]; \
      v2f P1 = (v2f){ yy.x*zz.x, -yy.x*zz.y }; \
      v2f P2 = (v2f){ -yy.y*zz.x,  yy.y*zz.y }; \
      gate_wire<i>(A0,A1,A2,A3,P1,P2,sb,a32); }
    IGATE(0) IGATE(1) IGATE(2) IGATE(3) IGATE(4) IGATE(5) IGATE(6) IGATE(7)
    #undef IGATE
  }

  // 3 entangling layers; rings 0,1 explicit (folded bpermute), ring 2 folded into readout
  const v2f* Ug2 = (const v2f*)Urot;
  #pragma unroll
  for (int l = 0; l < 3; ++l) {
    #define LGATE(i) { v2f P1 = Ug2[(l*8+(i))*2], P2 = Ug2[(l*8+(i))*2+1]; \
      gate_wire<i>(A0,A1,A2,A3,P1,P2,sb,a32); }
    LGATE(0) LGATE(1) LGATE(2) LGATE(3) LGATE(4) LGATE(5) LGATE(6) LGATE(7)
    #undef LGATE
    if (l < 2) {
      { v2f t = A2; A2 = A3; A3 = t; }              // CNOT(0,1): reg rename
      A0 = bperm2(addrA, A0); A2 = bperm2(addrA, A2);
      A1 = bperm2(addrB, A1); A3 = bperm2(addrB, A3);
      bool c0 = (lane & 1) != 0;                    // CNOT(7,0)
      v2f t0 = A0, t1 = A1;
      A0 = c0 ? A2 : A0; A2 = c0 ? t0 : A2;
      A1 = c0 ? A3 : A1; A3 = c0 ? t1 : A3;
    }
  }

  // ---- readout with ring-2 folded as parity signs ----
  float p0 = A0.x*A0.x + A0.y*A0.y;
  float p1 = A1.x*A1.x + A1.y*A1.y;
  float p2 = A2.x*A2.x + A2.y*A2.y;
  float p3 = A3.x*A3.x + A3.y*A3.y;
  float E = (p0 + p3) - (p1 + p2);   // sign (w0 xor w1) over regs
  float F = (p0 + p2) - (p1 + p3);   // sign (w1) over regs
  float Fv = xorf(F, (__popc(lane) & 1) << 31);  // all-lane-bit parity

  // cascade butterfly: S = plain sum, d_k = signed over masks {32..}
  float S = E, d1, d2, d3, d4, d5, d6;
  { float p = shx1<32>(S,a32); d1 = xorf(S-p, sb[0]); S += p; }
  { float p = shx1<16>(S,a32); S += p;
    float q = shx1<16>(d1,a32); d2 = xorf(d1-q, sb[1]); d1 += q; }
  { float p = shx1<8>(S,a32);  S += p;
    float q = shx1<8>(d1,a32); d1 += q;
    float r = shx1<8>(d2,a32); d3 = xorf(d2-r, sb[2]); d2 += r; }
  { float p = shx1<4>(S,a32);  S += p;
    float q = shx1<4>(d1,a32); d1 += q;
    float r = shx1<4>(d2,a32); d2 += r;
    float t = shx1<4>(d3,a32); d4 = xorf(d3-t, sb[3]); d3 += t; }
  { float p = shx1<2>(S,a32);  S += p;
    float q = shx1<2>(d1,a32); d1 += q;
    float r = shx1<2>(d2,a32); d2 += r;
    float t = shx1<2>(d3,a32); d3 += t;
    float w = shx1<2>(d4,a32); d5 = xorf(d4-w, sb[4]); d4 += w; }
  { float p = shx1<1>(S,a32);  S += p;
    float q = shx1<1>(d1,a32); d1 += q;
    float r = shx1<1>(d2,a32); d2 += r;
    float t = shx1<1>(d3,a32); d3 += t;
    float w = shx1<1>(d4,a32); d4 += w;
    float v = shx1<1>(d5,a32); d6 = xorf(d5-v, sb[5]); d5 += v; }
  Fv += shx1<32>(Fv,a32); Fv += shx1<16>(Fv,a32); Fv += shx1<8>(Fv,a32);
  Fv += shx1<4>(Fv,a32);  Fv += shx1<2>(Fv,a32);  Fv += shx1<1>(Fv,a32);
  const float z0 = Fv, z1 = S, z2 = d1, z3 = d2, z4 = d3, z5 = d4, z6 = d5, z7 = d6;

  // ---- output projection: rows 2*lane, 2*lane+1 of Wp (128x8) ----
  const int r0 = 2 * lane;
  const float4* wp = (const float4*)(Wp + r0 * 8);
  float4 w0v = wp[0], w1v = wp[1], w2v = wp[2], w3v = wp[3];
  float2 bpv = ((const float2*)bp)[lane];
  float o0 = bpv.x + z0*w0v.x + z1*w0v.y + z2*w0v.z + z3*w0v.w
                   + z4*w1v.x + z5*w1v.y + z6*w1v.z + z7*w1v.w;
  float o1 = bpv.y + z0*w2v.x + z1*w2v.y + z2*w2v.z + z3*w2v.w
                   + z4*w3v.x + z5*w3v.y + z6*w3v.z + z7*w3v.w;
  ((float2*)(out + (size_t)b * 128))[lane] = make_float2(o0, o1);
}

extern "C" void kernel_launch(void* const* d_in, const int* in_sizes, int n_in,
                              void* d_out, int out_size, void* d_ws, size_t ws_size,
                              hipStream_t stream) {
  const float* x  = (const float*)d_in[0];
  const float* W1 = (const float*)d_in[1];
  const float* b1 = (const float*)d_in[2];
  const float* W2 = (const float*)d_in[3];
  const float* b2 = (const float*)d_in[4];
  const float* W3 = (const float*)d_in[5];
  const float* b3 = (const float*)d_in[6];
  const float* qw = (const float*)d_in[7];
  const float* Wp = (const float*)d_in[8];
  const float* bp = (const float*)d_in[9];
  float* out = (float*)d_out;
  float* Urot = (float*)d_ws;   // 24 gates x 4 floats = 384 B

  const int B = in_sizes[0] / 80;
  prep_rot_kernel<<<1, 64, 0, stream>>>(qw, Urot);
  const int grid = (B + WPB - 1) / WPB;
  qblock_kernel<<<grid, 64 * WPB, 0, stream>>>(x, W1, b1, W2, b2, W3, b3,
                                               Urot, Wp, bp, out, B);
}

// Round 6
// 54.423 us; speedup vs baseline: 1.5889x; 1.1208x over previous
//
#include <hip/hip_runtime.h>

typedef float v2f __attribute__((ext_vector_type(2)));

#define WPB 4  // waves per block; each wave = 2 batch elements

__device__ __forceinline__ float xorf(float v, int sb) {
  return __int_as_float(__float_as_int(v) ^ sb);
}

// ---- VOP3P packed fp32 helpers (verified R3) ---------------------------
__device__ __forceinline__ v2f pkfma(v2f a, v2f b, v2f c) {
  v2f r; asm("v_pk_fma_f32 %0, %1, %2, %3" : "=v"(r) : "v"(a), "v"(b), "v"(c)); return r;
}
__device__ __forceinline__ v2f pkmul_bl(v2f c, v2f v) {
  v2f r; asm("v_pk_mul_f32 %0, %1, %2 op_sel:[0,0] op_sel_hi:[0,1]"
             : "=v"(r) : "v"(c), "v"(v)); return r;
}
__device__ __forceinline__ v2f pkfma_bl(v2f c, v2f v, v2f acc) {
  v2f r; asm("v_pk_fma_f32 %0, %1, %2, %3 op_sel:[0,0,0] op_sel_hi:[0,1,1]"
             : "=v"(r) : "v"(c), "v"(v), "v"(acc)); return r;
}
__device__ __forceinline__ v2f pkfma_bl_n(v2f c, v2f v, v2f acc) {
  v2f r; asm("v_pk_fma_f32 %0, %1, %2, %3 op_sel:[0,0,0] op_sel_hi:[0,1,1] neg_lo:[1,0,0] neg_hi:[1,0,0]"
             : "=v"(r) : "v"(c), "v"(v), "v"(acc)); return r;
}
__device__ __forceinline__ v2f pkfma_bh_i(v2f c, v2f v, v2f acc) {
  v2f r; asm("v_pk_fma_f32 %0, %1, %2, %3 op_sel:[1,1,0] op_sel_hi:[1,0,1] neg_lo:[1,0,0]"
             : "=v"(r) : "v"(c), "v"(v), "v"(acc)); return r;
}
__device__ __forceinline__ v2f pkfma_bh_mi(v2f c, v2f v, v2f acc) {
  v2f r; asm("v_pk_fma_f32 %0, %1, %2, %3 op_sel:[1,1,0] op_sel_hi:[1,0,1] neg_hi:[1,0,0]"
             : "=v"(r) : "v"(c), "v"(v), "v"(acc)); return r;
}

// ---- cross-lane xor exchange: verified DS prims + classic DPP ----------
// mask 32: ds_bpermute (R1-R3 verified); 16/4: ds_swizzle (verified);
// 8: DPP row_ror:8 (0x128, xor-8 within 16-lane row); 2/1: DPP quad_perm.
template<int M>
__device__ __forceinline__ float xch(float v, int a32) {
  if constexpr (M == 32)
    return __int_as_float(__builtin_amdgcn_ds_bpermute(a32, __float_as_int(v)));
  else if constexpr (M == 16 || M == 4)
    return __int_as_float(__builtin_amdgcn_ds_swizzle(__float_as_int(v), (M << 10) | 0x1f));
  else if constexpr (M == 8) {
    int i = __float_as_int(v);
    return __int_as_float(__builtin_amdgcn_update_dpp(i, i, 0x128, 0xF, 0xF, false));
  } else if constexpr (M == 2) {
    int i = __float_as_int(v);
    return __int_as_float(__builtin_amdgcn_update_dpp(i, i, 0x4E, 0xF, 0xF, false));
  } else {
    int i = __float_as_int(v);
    return __int_as_float(__builtin_amdgcn_update_dpp(i, i, 0xB1, 0xF, 0xF, false));
  }
}
template<int M>
__device__ __forceinline__ v2f xch2(v2f v, int a32) {
  v2f r; r.x = xch<M>(v.x, a32); r.y = xch<M>(v.y, a32); return r;
}
__device__ __forceinline__ v2f bperm2(int addr, v2f v) {
  v2f r;
  r.x = __int_as_float(__builtin_amdgcn_ds_bpermute(addr, __float_as_int(v.x)));
  r.y = __int_as_float(__builtin_amdgcn_ds_bpermute(addr, __float_as_int(v.y)));
  return r;
}

// ---- gate cores (verified R3) ------------------------------------------
// Rot-structured: P1=(A,Bc)=U00, P2=(C,D)=U01; U10=(-C,D), U11=(A,-Bc)
__device__ __forceinline__ void gpair(v2f& a, v2f& b, v2f P1, v2f P2) {
  v2f na = pkmul_bl(P1, a);
  na = pkfma_bh_i(P1, a, na);
  na = pkfma_bl(P2, b, na);
  na = pkfma_bh_i(P2, b, na);
  v2f nb = pkmul_bl(P1, b);
  nb = pkfma_bh_mi(P1, b, nb);
  nb = pkfma_bl_n(P2, a, nb);
  nb = pkfma_bh_i(P2, a, nb);
  a = na; b = nb;
}
__device__ __forceinline__ v2f glane(v2f a, v2f p, v2f P1, v2f P2) {
  v2f t = pkmul_bl(P1, a);
  t = pkfma_bh_i(P1, a, t);
  t = pkfma_bl(P2, p, t);
  t = pkfma_bh_i(P2, p, t);
  return t;
}

// wire W on one element's 4-reg state (reg bits = wires 0,1; lane bit 7-W = wire W)
template<int W>
__device__ __forceinline__ void gate_elem(v2f* S, v2f P1, v2f P2,
                                          const int* sb, int a32) {
  if constexpr (W == 0)      { gpair(S[0], S[2], P1, P2); gpair(S[1], S[3], P1, P2); }
  else if constexpr (W == 1) { gpair(S[0], S[1], P1, P2); gpair(S[2], S[3], P1, P2); }
  else {
    constexpr int M = 1 << (7 - W);
    const int s = sb[W - 2];
    v2f P1s = P1; P1s.y = xorf(P1.y, s);   // hi lanes: conj column
    v2f P2s = P2; P2s.x = xorf(P2.x, s);
    v2f p0 = xch2<M>(S[0], a32), p1 = xch2<M>(S[1], a32),
        p2 = xch2<M>(S[2], a32), p3 = xch2<M>(S[3], a32);
    S[0] = glane(S[0], p0, P1s, P2s); S[1] = glane(S[1], p1, P1s, P2s);
    S[2] = glane(S[2], p2, P1s, P2s); S[3] = glane(S[3], p3, P1s, P2s);
  }
}

__device__ __forceinline__ void cnot_ring(v2f* S, int addrA, int addrB, int lane) {
  { v2f t = S[2]; S[2] = S[3]; S[3] = t; }            // CNOT(0,1)
  S[0] = bperm2(addrA, S[0]); S[2] = bperm2(addrA, S[2]);
  S[1] = bperm2(addrB, S[1]); S[3] = bperm2(addrB, S[3]);
  bool c0 = (lane & 1) != 0;                          // CNOT(7,0)
  v2f t0 = S[0], t1 = S[1];
  S[0] = c0 ? S[2] : S[0]; S[2] = c0 ? t0 : S[2];
  S[1] = c0 ? S[3] : S[1]; S[3] = c0 ? t1 : S[3];
}

// readout with ring-2 folded as parity signs (R3-verified algebra, xch prims)
__device__ __forceinline__ void readout(const v2f* S, int lane, const int* sb,
                                        int a32, float* z) {
  float p0 = S[0].x*S[0].x + S[0].y*S[0].y;
  float p1 = S[1].x*S[1].x + S[1].y*S[1].y;
  float p2 = S[2].x*S[2].x + S[2].y*S[2].y;
  float p3 = S[3].x*S[3].x + S[3].y*S[3].y;
  float E = (p0 + p3) - (p1 + p2);
  float F = (p0 + p2) - (p1 + p3);
  float Fv = xorf(F, (__popc(lane) & 1) << 31);
  float Sm = E, d1, d2, d3, d4, d5, d6;
  { float p = xch<32>(Sm, a32); d1 = xorf(Sm - p, sb[0]); Sm += p; }
  { float p = xch<16>(Sm, a32); Sm += p;
    float q = xch<16>(d1, a32); d2 = xorf(d1 - q, sb[1]); d1 += q; }
  { float p = xch<8>(Sm, a32); Sm += p;
    float q = xch<8>(d1, a32); d1 += q;
    float r = xch<8>(d2, a32); d3 = xorf(d2 - r, sb[2]); d2 += r; }
  { float p = xch<4>(Sm, a32); Sm += p;
    float q = xch<4>(d1, a32); d1 += q;
    float r = xch<4>(d2, a32); d2 += r;
    float t = xch<4>(d3, a32); d4 = xorf(d3 - t, sb[3]); d3 += t; }
  { float p = xch<2>(Sm, a32); Sm += p;
    float q = xch<2>(d1, a32); d1 += q;
    float r = xch<2>(d2, a32); d2 += r;
    float t = xch<2>(d3, a32); d3 += t;
    float w = xch<2>(d4, a32); d5 = xorf(d4 - w, sb[4]); d4 += w; }
  { float p = xch<1>(Sm, a32); Sm += p;
    float q = xch<1>(d1, a32); d1 += q;
    float r = xch<1>(d2, a32); d2 += r;
    float t = xch<1>(d3, a32); d3 += t;
    float w = xch<1>(d4, a32); d4 += w;
    float v = xch<1>(d5, a32); d6 = xorf(d5 - v, sb[5]); d5 += v; }
  Fv += xch<32>(Fv, a32); Fv += xch<16>(Fv, a32); Fv += xch<8>(Fv, a32);
  Fv += xch<4>(Fv, a32);  Fv += xch<2>(Fv, a32);  Fv += xch<1>(Fv, a32);
  z[0] = Fv; z[1] = Sm; z[2] = d1; z[3] = d2;
  z[4] = d3; z[5] = d4; z[6] = d5; z[7] = d6;
}

__device__ __forceinline__ float fast_tanh(float x) {
  float e = __expf(2.f * x);
  return 1.f - 2.f * __builtin_amdgcn_rcpf(e + 1.f);
}
__device__ __forceinline__ v2f vlo(float4 v) { return (v2f){v.x, v.y}; }
__device__ __forceinline__ v2f vhi(float4 v) { return (v2f){v.z, v.w}; }

__global__ void prep_rot_kernel(const float* __restrict__ qw, float* __restrict__ U) {
  int t = threadIdx.x;
  if (t < 24) {
    float phi = qw[t*3+0], theta = qw[t*3+1], omega = qw[t*3+2];
    float st, ct; sincosf(0.5f*theta, &st, &ct);
    float sa, ca; sincosf(0.5f*(phi+omega), &sa, &ca);
    float sd, cd; sincosf(0.5f*(phi-omega), &sd, &cd);
    float4 o; o.x = ct*ca; o.y = -ct*sa; o.z = -st*cd; o.w = -st*sd;
    ((float4*)U)[t] = o;
  }
}

__global__ __launch_bounds__(64*WPB) void qblock_kernel(
    const float* __restrict__ x,  const float* __restrict__ W1, const float* __restrict__ b1,
    const float* __restrict__ W2, const float* __restrict__ b2,
    const float* __restrict__ W3, const float* __restrict__ b3,
    const float* __restrict__ Urot, const float* __restrict__ Wp, const float* __restrict__ bp,
    float* __restrict__ out, int B2)
{
  __shared__ float h1s[WPB][2][64];
  __shared__ float h2s[WPB][2][32];
  __shared__ v2f   cs [WPB][2][16];

  const int lane = threadIdx.x & 63;
  const int wv   = threadIdx.x >> 6;
  int bw = blockIdx.x * WPB + wv;
  if (bw >= B2) bw = B2 - 1;
  bw = __builtin_amdgcn_readfirstlane(bw);
  const int e0 = 2 * bw, e1 = e0 + 1;

  // ---- MLP layer 1: 80 -> 64, both elements share weight loads ----
  {
    const float4* xv0 = (const float4*)(x + (size_t)e0 * 80);
    const float4* xv1 = (const float4*)(x + (size_t)e1 * 80);
    const float4* wr  = (const float4*)(W1 + lane * 80);
    float bv = b1[lane];
    v2f a00 = (v2f){bv, 0.f}, a01 = (v2f){0.f, 0.f};
    v2f a10 = (v2f){bv, 0.f}, a11 = (v2f){0.f, 0.f};
    #pragma unroll
    for (int k = 0; k < 20; ++k) {
      float4 wk = wr[k], x0 = xv0[k], x1 = xv1[k];
      a00 = pkfma(vlo(x0), vlo(wk), a00); a01 = pkfma(vhi(x0), vhi(wk), a01);
      a10 = pkfma(vlo(x1), vlo(wk), a10); a11 = pkfma(vhi(x1), vhi(wk), a11);
    }
    h1s[wv][0][lane] = fast_tanh((a00.x + a00.y) + (a01.x + a01.y));
    h1s[wv][1][lane] = fast_tanh((a10.x + a10.y) + (a11.x + a11.y));
  }
  __threadfence_block();

  // ---- layer 2: 64 -> 32, all 64 lanes (elem = lane>>5) ----
  {
    const int e = lane >> 5, row = lane & 31;
    const float4* hv = (const float4*)(&h1s[wv][e][0]);
    const float4* wr = (const float4*)(W2 + row * 64);
    v2f ac0 = (v2f){b2[row], 0.f}, ac1 = (v2f){0.f, 0.f};
    #pragma unroll
    for (int k = 0; k < 16; ++k) {
      float4 hk = hv[k], wk = wr[k];
      ac0 = pkfma(vlo(hk), vlo(wk), ac0);
      ac1 = pkfma(vhi(hk), vhi(wk), ac1);
    }
    h2s[wv][e][row] = fast_tanh((ac0.x + ac0.y) + (ac1.x + ac1.y));
  }
  __threadfence_block();

  // ---- layer 3: 32 -> 16 angles, lanes 0..31 (elem = lane>>4) ----
  if (lane < 32) {
    const int e = lane >> 4, row = lane & 15;
    const float4* hv = (const float4*)(&h2s[wv][e][0]);
    const float4* wr = (const float4*)(W3 + row * 32);
    v2f ac0 = (v2f){b3[row], 0.f}, ac1 = (v2f){0.f, 0.f};
    #pragma unroll
    for (int k = 0; k < 8; ++k) {
      float4 hk = hv[k], wk = wr[k];
      ac0 = pkfma(vlo(hk), vlo(wk), ac0);
      ac1 = pkfma(vhi(hk), vhi(wk), ac1);
    }
    float sh, ch; __sincosf(0.5f * ((ac0.x + ac0.y) + (ac1.x + ac1.y)), &sh, &ch);
    cs[wv][e][row] = (v2f){ch, sh};
  }
  __threadfence_block();

  // ---- per-lane constants ----
  const int a32 = (lane ^ 32) << 2;
  const int sb[6] = { (lane&32)<<26, (lane&16)<<27, (lane&8)<<28,
                      (lane&4)<<29, (lane&2)<<30, (lane&1)<<31 };
  const int addrA = ((lane ^ (lane >> 1)) & 63) << 2;
  const int addrB = addrA ^ 128;

  // ---- two states: SA (elem0), SB (elem1) ----
  v2f SA[4], SB[4];
  #pragma unroll
  for (int i = 0; i < 4; ++i) { SA[i] = (v2f){0.f, 0.f}; SB[i] = (v2f){0.f, 0.f}; }
  if (lane == 0) { SA[0].x = 1.f; SB[0].x = 1.f; }

  // initial layer: fused U = RZ(a[i+8]) RY(a[i])
  #define IG(i) { \
    { v2f yy = cs[wv][0][i], zz = cs[wv][0][(i)+8]; \
      v2f P1 = (v2f){ yy.x*zz.x, -yy.x*zz.y }; \
      v2f P2 = (v2f){ -yy.y*zz.x,  yy.y*zz.y }; \
      gate_elem<i>(SA, P1, P2, sb, a32); } \
    { v2f yy = cs[wv][1][i], zz = cs[wv][1][(i)+8]; \
      v2f P1 = (v2f){ yy.x*zz.x, -yy.x*zz.y }; \
      v2f P2 = (v2f){ -yy.y*zz.x,  yy.y*zz.y }; \
      gate_elem<i>(SB, P1, P2, sb, a32); } }
  IG(0) IG(1) IG(2) IG(3) IG(4) IG(5) IG(6) IG(7)
  #undef IG

  // 3 entangling layers; rings 0,1 explicit, ring 2 folded into readout
  const v2f* Ug2 = (const v2f*)Urot;
  #pragma unroll
  for (int l = 0; l < 3; ++l) {
    #define LG(i) { v2f P1 = Ug2[(l*8+(i))*2], P2 = Ug2[(l*8+(i))*2+1]; \
      gate_elem<i>(SA, P1, P2, sb, a32); \
      gate_elem<i>(SB, P1, P2, sb, a32); }
    LG(0) LG(1) LG(2) LG(3) LG(4) LG(5) LG(6) LG(7)
    #undef LG
    if (l < 2) { cnot_ring(SA, addrA, addrB, lane); cnot_ring(SB, addrA, addrB, lane); }
  }

  // ---- readout + projection for both elements ----
  float zA[8], zB[8];
  readout(SA, lane, sb, a32, zA);
  readout(SB, lane, sb, a32, zB);

  const int r0 = 2 * lane;
  const float4* wp = (const float4*)(Wp + r0 * 8);
  float4 w0v = wp[0], w1v = wp[1], w2v = wp[2], w3v = wp[3];
  float2 bpv = ((const float2*)bp)[lane];
  {
    float o0 = bpv.x + zA[0]*w0v.x + zA[1]*w0v.y + zA[2]*w0v.z + zA[3]*w0v.w
                     + zA[4]*w1v.x + zA[5]*w1v.y + zA[6]*w1v.z + zA[7]*w1v.w;
    float o1 = bpv.y + zA[0]*w2v.x + zA[1]*w2v.y + zA[2]*w2v.z + zA[3]*w2v.w
                     + zA[4]*w3v.x + zA[5]*w3v.y + zA[6]*w3v.z + zA[7]*w3v.w;
    ((float2*)(out + (size_t)e0 * 128))[lane] = make_float2(o0, o1);
  }
  {
    float o0 = bpv.x + zB[0]*w0v.x + zB[1]*w0v.y + zB[2]*w0v.z + zB[3]*w0v.w
                     + zB[4]*w1v.x + zB[5]*w1v.y + zB[6]*w1v.z + zB[7]*w1v.w;
    float o1 = bpv.y + zB[0]*w2v.x + zB[1]*w2v.y + zB[2]*w2v.z + zB[3]*w2v.w
                     + zB[4]*w3v.x + zB[5]*w3v.y + zB[6]*w3v.z + zB[7]*w3v.w;
    ((float2*)(out + (size_t)e1 * 128))[lane] = make_float2(o0, o1);
  }
}

extern "C" void kernel_launch(void* const* d_in, const int* in_sizes, int n_in,
                              void* d_out, int out_size, void* d_ws, size_t ws_size,
                              hipStream_t stream) {
  const float* x  = (const float*)d_in[0];
  const float* W1 = (const float*)d_in[1];
  const float* b1 = (const float*)d_in[2];
  const float* W2 = (const float*)d_in[3];
  const float* b2 = (const float*)d_in[4];
  const float* W3 = (const float*)d_in[5];
  const float* b3 = (const float*)d_in[6];
  const float* qw = (const float*)d_in[7];
  const float* Wp = (const float*)d_in[8];
  const float* bp = (const float*)d_in[9];
  float* out = (float*)d_out;
  float* Urot = (float*)d_ws;

  const int B = in_sizes[0] / 80;
  const int B2 = B / 2;
  prep_rot_kernel<<<1, 64, 0, stream>>>(qw, Urot);
  const int grid = (B2 + WPB - 1) / WPB;
  qblock_kernel<<<grid, 64 * WPB, 0, stream>>>(x, W1, b1, W2, b2, W3, b3,
                                               Urot, Wp, bp, out, B2);
}

// Round 7
// 47.883 us; speedup vs baseline: 1.8059x; 1.1366x over previous
//
#include <hip/hip_runtime.h>

typedef float v2f __attribute__((ext_vector_type(2)));

#define WPB 4  // waves per block; each wave = 2 batch elements

__device__ __forceinline__ float xorf(float v, int sb) {
  return __int_as_float(__float_as_int(v) ^ sb);
}

// ---- VOP3P packed fp32 helpers; accumulating forms are in-place (+v) ----
__device__ __forceinline__ void pkfma_ip(v2f a, v2f b, v2f& acc) {
  asm("v_pk_fma_f32 %0, %1, %2, %0" : "+v"(acc) : "v"(a), "v"(b));
}
__device__ __forceinline__ v2f pkmul_bl(v2f c, v2f v) {
  v2f r; asm("v_pk_mul_f32 %0, %1, %2 op_sel:[0,0] op_sel_hi:[0,1]"
             : "=v"(r) : "v"(c), "v"(v)); return r;
}
__device__ __forceinline__ void pkfma_bl(v2f c, v2f v, v2f& acc) {
  asm("v_pk_fma_f32 %0, %1, %2, %0 op_sel:[0,0,0] op_sel_hi:[0,1,1]"
      : "+v"(acc) : "v"(c), "v"(v));
}
__device__ __forceinline__ void pkfma_bl_n(v2f c, v2f v, v2f& acc) {
  asm("v_pk_fma_f32 %0, %1, %2, %0 op_sel:[0,0,0] op_sel_hi:[0,1,1] neg_lo:[1,0,0] neg_hi:[1,0,0]"
      : "+v"(acc) : "v"(c), "v"(v));
}
__device__ __forceinline__ void pkfma_bh_i(v2f c, v2f v, v2f& acc) {
  asm("v_pk_fma_f32 %0, %1, %2, %0 op_sel:[1,1,0] op_sel_hi:[1,0,1] neg_lo:[1,0,0]"
      : "+v"(acc) : "v"(c), "v"(v));
}
__device__ __forceinline__ void pkfma_bh_mi(v2f c, v2f v, v2f& acc) {
  asm("v_pk_fma_f32 %0, %1, %2, %0 op_sel:[1,1,0] op_sel_hi:[1,0,1] neg_hi:[1,0,0]"
      : "+v"(acc) : "v"(c), "v"(v));
}
// full complex multiply r = a (x) b
__device__ __forceinline__ v2f cmul(v2f a, v2f b) {
  v2f r = pkmul_bl(a, b);
  pkfma_bh_i(a, b, r);
  return r;
}

// ---- cross-lane xor exchange (R6-verified prims) ------------------------
template<int M>
__device__ __forceinline__ float xch(float v, int a32) {
  if constexpr (M == 32)
    return __int_as_float(__builtin_amdgcn_ds_bpermute(a32, __float_as_int(v)));
  else if constexpr (M == 16 || M == 4)
    return __int_as_float(__builtin_amdgcn_ds_swizzle(__float_as_int(v), (M << 10) | 0x1f));
  else if constexpr (M == 8) {
    int i = __float_as_int(v);
    return __int_as_float(__builtin_amdgcn_update_dpp(i, i, 0x128, 0xF, 0xF, false));
  } else if constexpr (M == 2) {
    int i = __float_as_int(v);
    return __int_as_float(__builtin_amdgcn_update_dpp(i, i, 0x4E, 0xF, 0xF, false));
  } else {
    int i = __float_as_int(v);
    return __int_as_float(__builtin_amdgcn_update_dpp(i, i, 0xB1, 0xF, 0xF, false));
  }
}
template<int M>
__device__ __forceinline__ v2f xch2(v2f v, int a32) {
  v2f r; r.x = xch<M>(v.x, a32); r.y = xch<M>(v.y, a32); return r;
}
__device__ __forceinline__ v2f bperm2(int addr, v2f v) {
  v2f r;
  r.x = __int_as_float(__builtin_amdgcn_ds_bpermute(addr, __float_as_int(v.x)));
  r.y = __int_as_float(__builtin_amdgcn_ds_bpermute(addr, __float_as_int(v.y)));
  return r;
}

// ---- gate cores ---------------------------------------------------------
// SU(2): P1=(A,Bc)=U00, P2=(C,D)=U01; U10=-conj(P2), U11=conj(P1)
__device__ __forceinline__ void gpair(v2f& a, v2f& b, v2f P1, v2f P2) {
  v2f na = pkmul_bl(P1, a);
  pkfma_bh_i(P1, a, na);
  pkfma_bl(P2, b, na);
  pkfma_bh_i(P2, b, na);
  v2f nb = pkmul_bl(P1, b);
  pkfma_bh_mi(P1, b, nb);
  pkfma_bl_n(P2, a, nb);
  pkfma_bh_i(P2, a, nb);
  a = na; b = nb;
}
__device__ __forceinline__ v2f glane(v2f a, v2f p, v2f P1, v2f P2) {
  v2f t = pkmul_bl(P1, a);
  pkfma_bh_i(P1, a, t);
  pkfma_bl(P2, p, t);
  pkfma_bh_i(P2, p, t);
  return t;
}

// wire W on BOTH elements' states; signed coeffs computed once
template<int W>
__device__ __forceinline__ void gate_both(v2f* SA, v2f* SB, v2f P1, v2f P2,
                                          const int* sb, int a32) {
  if constexpr (W == 0) {
    gpair(SA[0], SA[2], P1, P2); gpair(SA[1], SA[3], P1, P2);
    gpair(SB[0], SB[2], P1, P2); gpair(SB[1], SB[3], P1, P2);
  } else if constexpr (W == 1) {
    gpair(SA[0], SA[1], P1, P2); gpair(SA[2], SA[3], P1, P2);
    gpair(SB[0], SB[1], P1, P2); gpair(SB[2], SB[3], P1, P2);
  } else {
    constexpr int M = 1 << (7 - W);
    const int s = sb[W - 2];
    v2f P1s = P1; P1s.y = xorf(P1.y, s);   // hi lanes: conj column
    v2f P2s = P2; P2s.x = xorf(P2.x, s);
    v2f pa0 = xch2<M>(SA[0], a32), pa1 = xch2<M>(SA[1], a32),
        pa2 = xch2<M>(SA[2], a32), pa3 = xch2<M>(SA[3], a32);
    v2f pb0 = xch2<M>(SB[0], a32), pb1 = xch2<M>(SB[1], a32),
        pb2 = xch2<M>(SB[2], a32), pb3 = xch2<M>(SB[3], a32);
    SA[0] = glane(SA[0], pa0, P1s, P2s); SA[1] = glane(SA[1], pa1, P1s, P2s);
    SA[2] = glane(SA[2], pa2, P1s, P2s); SA[3] = glane(SA[3], pa3, P1s, P2s);
    SB[0] = glane(SB[0], pb0, P1s, P2s); SB[1] = glane(SB[1], pb1, P1s, P2s);
    SB[2] = glane(SB[2], pb2, P1s, P2s); SB[3] = glane(SB[3], pb3, P1s, P2s);
  }
}

// product-state build: S[r] at lane = prod over wires of column-0 factor of W_i
// W_i = (layer-0 Rot_i) . (RZ_i . RY_i), stored in csW as float4 {P1, P2}
__device__ __forceinline__ void build_state(v2f* S, const float4* csW, int lane) {
  v2f g[6];
  #pragma unroll
  for (int w = 2; w < 8; ++w) {
    float4 c = csW[w];
    v2f P1 = (v2f){c.x, c.y};
    v2f nc2 = (v2f){-c.z, c.w};          // -conj(P2) = U10
    bool shi = ((lane >> (7 - w)) & 1) != 0;
    g[w - 2] = shi ? nc2 : P1;
  }
  v2f c23 = cmul(g[0], g[1]);
  v2f c45 = cmul(g[2], g[3]);
  v2f c67 = cmul(g[4], g[5]);
  v2f common = cmul(c23, cmul(c45, c67));
  float4 c0 = csW[0], c1 = csW[1];
  v2f P10 = (v2f){c0.x, c0.y}, m0 = (v2f){-c0.z, c0.w};
  v2f P11 = (v2f){c1.x, c1.y}, m1 = (v2f){-c1.z, c1.w};
  S[0] = cmul(cmul(P10, P11), common);
  S[1] = cmul(cmul(P10, m1 ), common);
  S[2] = cmul(cmul(m0 , P11), common);
  S[3] = cmul(cmul(m0 , m1 ), common);
}

__device__ __forceinline__ void cnot_ring(v2f* S, int addrA, int addrB, int lane) {
  { v2f t = S[2]; S[2] = S[3]; S[3] = t; }            // CNOT(0,1)
  S[0] = bperm2(addrA, S[0]); S[2] = bperm2(addrA, S[2]);
  S[1] = bperm2(addrB, S[1]); S[3] = bperm2(addrB, S[3]);
  bool c0 = (lane & 1) != 0;                          // CNOT(7,0)
  v2f t0 = S[0], t1 = S[1];
  S[0] = c0 ? S[2] : S[0]; S[2] = c0 ? t0 : S[2];
  S[1] = c0 ? S[3] : S[1]; S[3] = c0 ? t1 : S[3];
}

// readout with ring-2 folded as parity signs (R3/R6-verified)
__device__ __forceinline__ void readout(const v2f* S, int lane, const int* sb,
                                        int a32, float* z) {
  float p0 = S[0].x*S[0].x + S[0].y*S[0].y;
  float p1 = S[1].x*S[1].x + S[1].y*S[1].y;
  float p2 = S[2].x*S[2].x + S[2].y*S[2].y;
  float p3 = S[3].x*S[3].x + S[3].y*S[3].y;
  float E = (p0 + p3) - (p1 + p2);
  float F = (p0 + p2) - (p1 + p3);
  float Fv = xorf(F, (__popc(lane) & 1) << 31);
  float Sm = E, d1, d2, d3, d4, d5, d6;
  { float p = xch<32>(Sm, a32); d1 = xorf(Sm - p, sb[0]); Sm += p; }
  { float p = xch<16>(Sm, a32); Sm += p;
    float q = xch<16>(d1, a32); d2 = xorf(d1 - q, sb[1]); d1 += q; }
  { float p = xch<8>(Sm, a32); Sm += p;
    float q = xch<8>(d1, a32); d1 += q;
    float r = xch<8>(d2, a32); d3 = xorf(d2 - r, sb[2]); d2 += r; }
  { float p = xch<4>(Sm, a32); Sm += p;
    float q = xch<4>(d1, a32); d1 += q;
    float r = xch<4>(d2, a32); d2 += r;
    float t = xch<4>(d3, a32); d4 = xorf(d3 - t, sb[3]); d3 += t; }
  { float p = xch<2>(Sm, a32); Sm += p;
    float q = xch<2>(d1, a32); d1 += q;
    float r = xch<2>(d2, a32); d2 += r;
    float t = xch<2>(d3, a32); d3 += t;
    float w = xch<2>(d4, a32); d5 = xorf(d4 - w, sb[4]); d4 += w; }
  { float p = xch<1>(Sm, a32); Sm += p;
    float q = xch<1>(d1, a32); d1 += q;
    float r = xch<1>(d2, a32); d2 += r;
    float t = xch<1>(d3, a32); d3 += t;
    float w = xch<1>(d4, a32); d4 += w;
    float v = xch<1>(d5, a32); d6 = xorf(d5 - v, sb[5]); d5 += v; }
  Fv += xch<32>(Fv, a32); Fv += xch<16>(Fv, a32); Fv += xch<8>(Fv, a32);
  Fv += xch<4>(Fv, a32);  Fv += xch<2>(Fv, a32);  Fv += xch<1>(Fv, a32);
  z[0] = Fv; z[1] = Sm; z[2] = d1; z[3] = d2;
  z[4] = d3; z[5] = d4; z[6] = d5; z[7] = d6;
}

__device__ __forceinline__ float fast_tanh(float x) {
  float e = __expf(2.f * x);
  return 1.f - 2.f * __builtin_amdgcn_rcpf(e + 1.f);
}
__device__ __forceinline__ v2f vlo(float4 v) { return (v2f){v.x, v.y}; }
__device__ __forceinline__ v2f vhi(float4 v) { return (v2f){v.z, v.w}; }

__global__ void prep_rot_kernel(const float* __restrict__ qw, float* __restrict__ U) {
  int t = threadIdx.x;
  if (t < 24) {
    float phi = qw[t*3+0], theta = qw[t*3+1], omega = qw[t*3+2];
    float st, ct; sincosf(0.5f*theta, &st, &ct);
    float sa, ca; sincosf(0.5f*(phi+omega), &sa, &ca);
    float sd, cd; sincosf(0.5f*(phi-omega), &sd, &cd);
    float4 o; o.x = ct*ca; o.y = -ct*sa; o.z = -st*cd; o.w = -st*sd;
    ((float4*)U)[t] = o;
  }
}

__global__ __launch_bounds__(64*WPB) void qblock_kernel(
    const float* __restrict__ x,  const float* __restrict__ W1, const float* __restrict__ b1,
    const float* __restrict__ W2, const float* __restrict__ b2,
    const float* __restrict__ W3, const float* __restrict__ b3,
    const float* __restrict__ Urot, const float* __restrict__ Wp, const float* __restrict__ bp,
    float* __restrict__ out, int B2)
{
  __shared__ float  h1s[WPB][2][64];
  __shared__ float  h2s[WPB][2][32];
  __shared__ v2f    cs [WPB][2][16];
  __shared__ float4 csW[WPB][2][8];   // combined W = Rot_l0 . RZ . RY per wire

  const int lane = threadIdx.x & 63;
  const int wv   = threadIdx.x >> 6;
  int bw = blockIdx.x * WPB + wv;
  if (bw >= B2) bw = B2 - 1;
  bw = __builtin_amdgcn_readfirstlane(bw);
  const int e0 = 2 * bw, e1 = e0 + 1;
  const v2f* Ug2 = (const v2f*)Urot;

  // ---- MLP layer 1: 80 -> 64, both elements share weight loads ----
  {
    const float4* xv0 = (const float4*)(x + (size_t)e0 * 80);
    const float4* xv1 = (const float4*)(x + (size_t)e1 * 80);
    const float4* wr  = (const float4*)(W1 + lane * 80);
    float bv = b1[lane];
    v2f a00 = (v2f){bv, 0.f}, a01 = (v2f){0.f, 0.f};
    v2f a10 = (v2f){bv, 0.f}, a11 = (v2f){0.f, 0.f};
    #pragma unroll
    for (int k = 0; k < 20; ++k) {
      float4 wk = wr[k], x0 = xv0[k], x1 = xv1[k];
      pkfma_ip(vlo(x0), vlo(wk), a00); pkfma_ip(vhi(x0), vhi(wk), a01);
      pkfma_ip(vlo(x1), vlo(wk), a10); pkfma_ip(vhi(x1), vhi(wk), a11);
    }
    h1s[wv][0][lane] = fast_tanh((a00.x + a00.y) + (a01.x + a01.y));
    h1s[wv][1][lane] = fast_tanh((a10.x + a10.y) + (a11.x + a11.y));
  }
  __threadfence_block();

  // ---- layer 2: 64 -> 32, all 64 lanes (elem = lane>>5) ----
  {
    const int e = lane >> 5, row = lane & 31;
    const float4* hv = (const float4*)(&h1s[wv][e][0]);
    const float4* wr = (const float4*)(W2 + row * 64);
    v2f ac0 = (v2f){b2[row], 0.f}, ac1 = (v2f){0.f, 0.f};
    #pragma unroll
    for (int k = 0; k < 16; ++k) {
      float4 hk = hv[k], wk = wr[k];
      pkfma_ip(vlo(hk), vlo(wk), ac0);
      pkfma_ip(vhi(hk), vhi(wk), ac1);
    }
    h2s[wv][e][row] = fast_tanh((ac0.x + ac0.y) + (ac1.x + ac1.y));
  }
  __threadfence_block();

  // ---- layer 3: 32 -> 16 angles, lanes 0..31 (elem = lane>>4) ----
  if (lane < 32) {
    const int e = lane >> 4, row = lane & 15;
    const float4* hv = (const float4*)(&h2s[wv][e][0]);
    const float4* wr = (const float4*)(W3 + row * 32);
    v2f ac0 = (v2f){b3[row], 0.f}, ac1 = (v2f){0.f, 0.f};
    #pragma unroll
    for (int k = 0; k < 8; ++k) {
      float4 hk = hv[k], wk = wr[k];
      pkfma_ip(vlo(hk), vlo(wk), ac0);
      pkfma_ip(vhi(hk), vhi(wk), ac1);
    }
    float sh, ch; __sincosf(0.5f * ((ac0.x + ac0.y) + (ac1.x + ac1.y)), &sh, &ch);
    cs[wv][e][row] = (v2f){ch, sh};
  }
  __threadfence_block();

  // ---- combine W_i = Rot_l0_i . (RZ_i . RY_i): 8 lanes per elem ----
  if (lane < 32) {
    const int e = lane >> 4, k = lane & 15;
    if (k < 8) {
      v2f yy = cs[wv][e][k], zz = cs[wv][e][k + 8];
      v2f u1 = (v2f){  yy.x * zz.x, -yy.x * zz.y };   // U00 of RZ.RY
      v2f u2 = (v2f){ -yy.y * zz.x,  yy.y * zz.y };   // U01
      v2f cu1 = (v2f){ u1.x, -u1.y };
      v2f cu2 = (v2f){ u2.x, -u2.y };
      v2f r1 = Ug2[2 * k], r2 = Ug2[2 * k + 1];
      v2f P1c = cmul(r1, u1);            // r1 (x) u1 - r2 (x) conj(u2)
      pkfma_bl_n(r2, cu2, P1c);
      pkfma_bh_mi(r2, cu2, P1c);
      v2f P2c = cmul(r1, u2);            // r1 (x) u2 + r2 (x) conj(u1)
      pkfma_bl(r2, cu1, P2c);
      pkfma_bh_i(r2, cu1, P2c);
      csW[wv][e][k] = make_float4(P1c.x, P1c.y, P2c.x, P2c.y);
    }
  }
  __threadfence_block();

  // ---- per-lane constants ----
  const int a32 = (lane ^ 32) << 2;
  const int sb[6] = { (lane&32)<<26, (lane&16)<<27, (lane&8)<<28,
                      (lane&4)<<29, (lane&2)<<30, (lane&1)<<31 };
  const int addrA = ((lane ^ (lane >> 1)) & 63) << 2;
  const int addrB = addrA ^ 128;

  // ---- build product states (init + layer-0 Rot folded), then ring 0 ----
  v2f SA[4], SB[4];
  build_state(SA, &csW[wv][0][0], lane);
  build_state(SB, &csW[wv][1][0], lane);
  cnot_ring(SA, addrA, addrB, lane); cnot_ring(SB, addrA, addrB, lane);

  // ---- layers 1,2; ring 1 explicit, ring 2 folded into readout ----
  #define LGB(l, i) { v2f P1 = Ug2[((l)*8+(i))*2], P2 = Ug2[((l)*8+(i))*2+1]; \
    gate_both<i>(SA, SB, P1, P2, sb, a32); }
  LGB(1,0) LGB(1,1) LGB(1,2) LGB(1,3) LGB(1,4) LGB(1,5) LGB(1,6) LGB(1,7)
  cnot_ring(SA, addrA, addrB, lane); cnot_ring(SB, addrA, addrB, lane);
  LGB(2,0) LGB(2,1) LGB(2,2) LGB(2,3) LGB(2,4) LGB(2,5) LGB(2,6) LGB(2,7)
  #undef LGB

  // ---- readout + projection for both elements ----
  float zA[8], zB[8];
  readout(SA, lane, sb, a32, zA);
  readout(SB, lane, sb, a32, zB);

  const int r0 = 2 * lane;
  const float4* wp = (const float4*)(Wp + r0 * 8);
  float4 w0v = wp[0], w1v = wp[1], w2v = wp[2], w3v = wp[3];
  float2 bpv = ((const float2*)bp)[lane];
  {
    float o0 = bpv.x + zA[0]*w0v.x + zA[1]*w0v.y + zA[2]*w0v.z + zA[3]*w0v.w
                     + zA[4]*w1v.x + zA[5]*w1v.y + zA[6]*w1v.z + zA[7]*w1v.w;
    float o1 = bpv.y + zA[0]*w2v.x + zA[1]*w2v.y + zA[2]*w2v.z + zA[3]*w2v.w
                     + zA[4]*w3v.x + zA[5]*w3v.y + zA[6]*w3v.z + zA[7]*w3v.w;
    ((float2*)(out + (size_t)e0 * 128))[lane] = make_float2(o0, o1);
  }
  {
    float o0 = bpv.x + zB[0]*w0v.x + zB[1]*w0v.y + zB[2]*w0v.z + zB[3]*w0v.w
                     + zB[4]*w1v.x + zB[5]*w1v.y + zB[6]*w1v.z + zB[7]*w1v.w;
    float o1 = bpv.y + zB[0]*w2v.x + zB[1]*w2v.y + zB[2]*w2v.z + zB[3]*w2v.w
                     + zB[4]*w3v.x + zB[5]*w3v.y + zB[6]*w3v.z + zB[7]*w3v.w;
    ((float2*)(out + (size_t)e1 * 128))[lane] = make_float2(o0, o1);
  }
}

extern "C" void kernel_launch(void* const* d_in, const int* in_sizes, int n_in,
                              void* d_out, int out_size, void* d_ws, size_t ws_size,
                              hipStream_t stream) {
  const float* x  = (const float*)d_in[0];
  const float* W1 = (const float*)d_in[1];
  const float* b1 = (const float*)d_in[2];
  const float* W2 = (const float*)d_in[3];
  const float* b2 = (const float*)d_in[4];
  const float* W3 = (const float*)d_in[5];
  const float* b3 = (const float*)d_in[6];
  const float* qw = (const float*)d_in[7];
  const float* Wp = (const float*)d_in[8];
  const float* bp = (const float*)d_in[9];
  float* out = (float*)d_out;
  float* Urot = (float*)d_ws;

  const int B = in_sizes[0] / 80;
  const int B2 = B / 2;
  prep_rot_kernel<<<1, 64, 0, stream>>>(qw, Urot);
  const int grid = (B2 + WPB - 1) / WPB;
  qblock_kernel<<<grid, 64 * WPB, 0, stream>>>(x, W1, b1, W2, b2, W3, b3,
                                               Urot, Wp, bp, out, B2);
}

// Round 8
// 42.199 us; speedup vs baseline: 2.0491x; 1.1347x over previous
//
#include <hip/hip_runtime.h>

typedef float v2f __attribute__((ext_vector_type(2)));

#define WPB 4   // waves per block; each wave = 4 batch elements
#define NE  4

__device__ __forceinline__ float xorf(float v, int sb) {
  return __int_as_float(__float_as_int(v) ^ sb);
}

// ---- VOP3P packed fp32 helpers; accumulating forms in-place (+v) --------
__device__ __forceinline__ void pkfma_ip(v2f a, v2f b, v2f& acc) {
  asm("v_pk_fma_f32 %0, %1, %2, %0" : "+v"(acc) : "v"(a), "v"(b));
}
__device__ __forceinline__ v2f pkmul_bl(v2f c, v2f v) {
  v2f r; asm("v_pk_mul_f32 %0, %1, %2 op_sel:[0,0] op_sel_hi:[0,1]"
             : "=v"(r) : "v"(c), "v"(v)); return r;
}
__device__ __forceinline__ void pkfma_bl(v2f c, v2f v, v2f& acc) {
  asm("v_pk_fma_f32 %0, %1, %2, %0 op_sel:[0,0,0] op_sel_hi:[0,1,1]"
      : "+v"(acc) : "v"(c), "v"(v));
}
__device__ __forceinline__ void pkfma_bl_n(v2f c, v2f v, v2f& acc) {
  asm("v_pk_fma_f32 %0, %1, %2, %0 op_sel:[0,0,0] op_sel_hi:[0,1,1] neg_lo:[1,0,0] neg_hi:[1,0,0]"
      : "+v"(acc) : "v"(c), "v"(v));
}
__device__ __forceinline__ void pkfma_bh_i(v2f c, v2f v, v2f& acc) {
  asm("v_pk_fma_f32 %0, %1, %2, %0 op_sel:[1,1,0] op_sel_hi:[1,0,1] neg_lo:[1,0,0]"
      : "+v"(acc) : "v"(c), "v"(v));
}
__device__ __forceinline__ void pkfma_bh_mi(v2f c, v2f v, v2f& acc) {
  asm("v_pk_fma_f32 %0, %1, %2, %0 op_sel:[1,1,0] op_sel_hi:[1,0,1] neg_hi:[1,0,0]"
      : "+v"(acc) : "v"(c), "v"(v));
}
__device__ __forceinline__ v2f cmul(v2f a, v2f b) {
  v2f r = pkmul_bl(a, b);
  pkfma_bh_i(a, b, r);
  return r;
}

// ---- cross-lane xor exchange (R6-verified prims) ------------------------
template<int M>
__device__ __forceinline__ float xch(float v, int a32) {
  if constexpr (M == 32)
    return __int_as_float(__builtin_amdgcn_ds_bpermute(a32, __float_as_int(v)));
  else if constexpr (M == 16 || M == 4)
    return __int_as_float(__builtin_amdgcn_ds_swizzle(__float_as_int(v), (M << 10) | 0x1f));
  else if constexpr (M == 8) {
    int i = __float_as_int(v);
    return __int_as_float(__builtin_amdgcn_update_dpp(i, i, 0x128, 0xF, 0xF, false));
  } else if constexpr (M == 2) {
    int i = __float_as_int(v);
    return __int_as_float(__builtin_amdgcn_update_dpp(i, i, 0x4E, 0xF, 0xF, false));
  } else {
    int i = __float_as_int(v);
    return __int_as_float(__builtin_amdgcn_update_dpp(i, i, 0xB1, 0xF, 0xF, false));
  }
}
template<int M>
__device__ __forceinline__ v2f xch2(v2f v, int a32) {
  v2f r; r.x = xch<M>(v.x, a32); r.y = xch<M>(v.y, a32); return r;
}
__device__ __forceinline__ v2f bperm2(int addr, v2f v) {
  v2f r;
  r.x = __int_as_float(__builtin_amdgcn_ds_bpermute(addr, __float_as_int(v.x)));
  r.y = __int_as_float(__builtin_amdgcn_ds_bpermute(addr, __float_as_int(v.y)));
  return r;
}

// ---- gate cores (R7-verified) -------------------------------------------
__device__ __forceinline__ void gpair(v2f& a, v2f& b, v2f P1, v2f P2) {
  v2f na = pkmul_bl(P1, a);
  pkfma_bh_i(P1, a, na);
  pkfma_bl(P2, b, na);
  pkfma_bh_i(P2, b, na);
  v2f nb = pkmul_bl(P1, b);
  pkfma_bh_mi(P1, b, nb);
  pkfma_bl_n(P2, a, nb);
  pkfma_bh_i(P2, a, nb);
  a = na; b = nb;
}
__device__ __forceinline__ v2f glane(v2f a, v2f p, v2f P1, v2f P2) {
  v2f t = pkmul_bl(P1, a);
  pkfma_bh_i(P1, a, t);
  pkfma_bl(P2, p, t);
  pkfma_bh_i(P2, p, t);
  return t;
}

// wire W on ALL NE elements' states; signed coeffs computed once
template<int W>
__device__ __forceinline__ void gate_all(v2f* S, v2f P1, v2f P2,
                                         const int* sb, int a32) {
  if constexpr (W == 0) {
    #pragma unroll
    for (int e = 0; e < NE; ++e) {
      gpair(S[4*e+0], S[4*e+2], P1, P2); gpair(S[4*e+1], S[4*e+3], P1, P2);
    }
  } else if constexpr (W == 1) {
    #pragma unroll
    for (int e = 0; e < NE; ++e) {
      gpair(S[4*e+0], S[4*e+1], P1, P2); gpair(S[4*e+2], S[4*e+3], P1, P2);
    }
  } else {
    constexpr int M = 1 << (7 - W);
    const int s = sb[W - 2];
    v2f P1s = P1; P1s.y = xorf(P1.y, s);
    v2f P2s = P2; P2s.x = xorf(P2.x, s);
    #pragma unroll
    for (int e = 0; e < NE; ++e) {
      v2f p0 = xch2<M>(S[4*e+0], a32), p1 = xch2<M>(S[4*e+1], a32),
          p2 = xch2<M>(S[4*e+2], a32), p3 = xch2<M>(S[4*e+3], a32);
      S[4*e+0] = glane(S[4*e+0], p0, P1s, P2s);
      S[4*e+1] = glane(S[4*e+1], p1, P1s, P2s);
      S[4*e+2] = glane(S[4*e+2], p2, P1s, P2s);
      S[4*e+3] = glane(S[4*e+3], p3, P1s, P2s);
    }
  }
}

// product-state build (init + layer-0 Rot folded)
__device__ __forceinline__ void build_state(v2f* S, const float4* csW, int lane) {
  v2f g[6];
  #pragma unroll
  for (int w = 2; w < 8; ++w) {
    float4 c = csW[w];
    v2f P1 = (v2f){c.x, c.y};
    v2f nc2 = (v2f){-c.z, c.w};
    bool shi = ((lane >> (7 - w)) & 1) != 0;
    g[w - 2] = shi ? nc2 : P1;
  }
  v2f c23 = cmul(g[0], g[1]);
  v2f c45 = cmul(g[2], g[3]);
  v2f c67 = cmul(g[4], g[5]);
  v2f common = cmul(c23, cmul(c45, c67));
  float4 c0 = csW[0], c1 = csW[1];
  v2f P10 = (v2f){c0.x, c0.y}, m0 = (v2f){-c0.z, c0.w};
  v2f P11 = (v2f){c1.x, c1.y}, m1 = (v2f){-c1.z, c1.w};
  S[0] = cmul(cmul(P10, P11), common);
  S[1] = cmul(cmul(P10, m1 ), common);
  S[2] = cmul(cmul(m0 , P11), common);
  S[3] = cmul(cmul(m0 , m1 ), common);
}

__device__ __forceinline__ void cnot_ring(v2f* S, int addrA, int addrB, int lane) {
  { v2f t = S[2]; S[2] = S[3]; S[3] = t; }
  S[0] = bperm2(addrA, S[0]); S[2] = bperm2(addrA, S[2]);
  S[1] = bperm2(addrB, S[1]); S[3] = bperm2(addrB, S[3]);
  bool c0 = (lane & 1) != 0;
  v2f t0 = S[0], t1 = S[1];
  S[0] = c0 ? S[2] : S[0]; S[2] = c0 ? t0 : S[2];
  S[1] = c0 ? S[3] : S[1]; S[3] = c0 ? t1 : S[3];
}

// readout with ring-2 folded as parity signs (R3/R6-verified)
__device__ __forceinline__ void readout(const v2f* S, int lane, const int* sb,
                                        int a32, float* z) {
  float p0 = S[0].x*S[0].x + S[0].y*S[0].y;
  float p1 = S[1].x*S[1].x + S[1].y*S[1].y;
  float p2 = S[2].x*S[2].x + S[2].y*S[2].y;
  float p3 = S[3].x*S[3].x + S[3].y*S[3].y;
  float E = (p0 + p3) - (p1 + p2);
  float F = (p0 + p2) - (p1 + p3);
  float Fv = xorf(F, (__popc(lane) & 1) << 31);
  float Sm = E, d1, d2, d3, d4, d5, d6;
  { float p = xch<32>(Sm, a32); d1 = xorf(Sm - p, sb[0]); Sm += p; }
  { float p = xch<16>(Sm, a32); Sm += p;
    float q = xch<16>(d1, a32); d2 = xorf(d1 - q, sb[1]); d1 += q; }
  { float p = xch<8>(Sm, a32); Sm += p;
    float q = xch<8>(d1, a32); d1 += q;
    float r = xch<8>(d2, a32); d3 = xorf(d2 - r, sb[2]); d2 += r; }
  { float p = xch<4>(Sm, a32); Sm += p;
    float q = xch<4>(d1, a32); d1 += q;
    float r = xch<4>(d2, a32); d2 += r;
    float t = xch<4>(d3, a32); d4 = xorf(d3 - t, sb[3]); d3 += t; }
  { float p = xch<2>(Sm, a32); Sm += p;
    float q = xch<2>(d1, a32); d1 += q;
    float r = xch<2>(d2, a32); d2 += r;
    float t = xch<2>(d3, a32); d3 += t;
    float w = xch<2>(d4, a32); d5 = xorf(d4 - w, sb[4]); d4 += w; }
  { float p = xch<1>(Sm, a32); Sm += p;
    float q = xch<1>(d1, a32); d1 += q;
    float r = xch<1>(d2, a32); d2 += r;
    float t = xch<1>(d3, a32); d3 += t;
    float w = xch<1>(d4, a32); d4 += w;
    float v = xch<1>(d5, a32); d6 = xorf(d5 - v, sb[5]); d5 += v; }
  Fv += xch<32>(Fv, a32); Fv += xch<16>(Fv, a32); Fv += xch<8>(Fv, a32);
  Fv += xch<4>(Fv, a32);  Fv += xch<2>(Fv, a32);  Fv += xch<1>(Fv, a32);
  z[0] = Fv; z[1] = Sm; z[2] = d1; z[3] = d2;
  z[4] = d3; z[5] = d4; z[6] = d5; z[7] = d6;
}

__device__ __forceinline__ float fast_tanh(float x) {
  float e = __expf(2.f * x);
  return 1.f - 2.f * __builtin_amdgcn_rcpf(e + 1.f);
}
__device__ __forceinline__ v2f vlo(float4 v) { return (v2f){v.x, v.y}; }
__device__ __forceinline__ v2f vhi(float4 v) { return (v2f){v.z, v.w}; }

__global__ void prep_rot_kernel(const float* __restrict__ qw, float* __restrict__ U) {
  int t = threadIdx.x;
  if (t < 24) {
    float phi = qw[t*3+0], theta = qw[t*3+1], omega = qw[t*3+2];
    float st, ct; sincosf(0.5f*theta, &st, &ct);
    float sa, ca; sincosf(0.5f*(phi+omega), &sa, &ca);
    float sd, cd; sincosf(0.5f*(phi-omega), &sd, &cd);
    float4 o; o.x = ct*ca; o.y = -ct*sa; o.z = -st*cd; o.w = -st*sd;
    ((float4*)U)[t] = o;
  }
}

__global__ __launch_bounds__(64*WPB) void qblock_kernel(
    const float* __restrict__ x,  const float* __restrict__ W1, const float* __restrict__ b1,
    const float* __restrict__ W2, const float* __restrict__ b2,
    const float* __restrict__ W3, const float* __restrict__ b3,
    const float* __restrict__ Urot, const float* __restrict__ Wp, const float* __restrict__ bp,
    float* __restrict__ out, int B4)
{
  __shared__ float  h1s[WPB][NE][64];
  __shared__ float  h2s[WPB][NE][32];
  __shared__ v2f    cs [WPB][NE][16];
  __shared__ float4 csW[WPB][NE][8];

  const int lane = threadIdx.x & 63;
  const int wv   = threadIdx.x >> 6;
  int bw = blockIdx.x * WPB + wv;
  if (bw >= B4) bw = B4 - 1;
  bw = __builtin_amdgcn_readfirstlane(bw);
  const int e0 = NE * bw;
  const v2f* Ug2 = (const v2f*)Urot;

  // ---- MLP layer 1: 80 -> 64 for 4 elements, shared weight loads ----
  {
    const float4* wr = (const float4*)(W1 + lane * 80);
    float bv = b1[lane];
    v2f a0[NE], a1[NE];
    #pragma unroll
    for (int e = 0; e < NE; ++e) { a0[e] = (v2f){bv, 0.f}; a1[e] = (v2f){0.f, 0.f}; }
    #pragma unroll
    for (int k = 0; k < 20; ++k) {
      float4 wk = wr[k];
      #pragma unroll
      for (int e = 0; e < NE; ++e) {
        float4 xk = ((const float4*)(x + (size_t)(e0 + e) * 80))[k];
        pkfma_ip(vlo(xk), vlo(wk), a0[e]);
        pkfma_ip(vhi(xk), vhi(wk), a1[e]);
      }
    }
    #pragma unroll
    for (int e = 0; e < NE; ++e)
      h1s[wv][e][lane] = fast_tanh((a0[e].x + a0[e].y) + (a1[e].x + a1[e].y));
  }
  __threadfence_block();

  // ---- layer 2: 64 -> 32; lane = (epair, row): 2 elems per lane, 1 W-row ----
  {
    const int ep = lane >> 5, row = lane & 31;
    const float4* wr = (const float4*)(W2 + row * 64);
    const float4* hvA = (const float4*)(&h1s[wv][2*ep+0][0]);
    const float4* hvB = (const float4*)(&h1s[wv][2*ep+1][0]);
    v2f aA0 = (v2f){b2[row], 0.f}, aA1 = (v2f){0.f, 0.f};
    v2f aB0 = aA0, aB1 = aA1;
    #pragma unroll
    for (int k = 0; k < 16; ++k) {
      float4 wk = wr[k], hA = hvA[k], hB = hvB[k];
      pkfma_ip(vlo(hA), vlo(wk), aA0); pkfma_ip(vhi(hA), vhi(wk), aA1);
      pkfma_ip(vlo(hB), vlo(wk), aB0); pkfma_ip(vhi(hB), vhi(wk), aB1);
    }
    h2s[wv][2*ep+0][row] = fast_tanh((aA0.x + aA0.y) + (aA1.x + aA1.y));
    h2s[wv][2*ep+1][row] = fast_tanh((aB0.x + aB0.y) + (aB1.x + aB1.y));
  }
  __threadfence_block();

  // ---- layer 3: 32 -> 16 angles; lane = (elem, row), all 64 lanes ----
  {
    const int e = lane >> 4, row = lane & 15;
    const float4* hv = (const float4*)(&h2s[wv][e][0]);
    const float4* wr = (const float4*)(W3 + row * 32);
    v2f ac0 = (v2f){b3[row], 0.f}, ac1 = (v2f){0.f, 0.f};
    #pragma unroll
    for (int k = 0; k < 8; ++k) {
      float4 hk = hv[k], wk = wr[k];
      pkfma_ip(vlo(hk), vlo(wk), ac0);
      pkfma_ip(vhi(hk), vhi(wk), ac1);
    }
    float sh, ch; __sincosf(0.5f * ((ac0.x + ac0.y) + (ac1.x + ac1.y)), &sh, &ch);
    cs[wv][e][row] = (v2f){ch, sh};
  }
  __threadfence_block();

  // ---- combine W_i = Rot_l0_i . (RZ_i . RY_i): 8 lanes per elem ----
  if (lane < 32) {
    const int e = lane >> 3, k = lane & 7;
    v2f yy = cs[wv][e][k], zz = cs[wv][e][k + 8];
    v2f u1 = (v2f){  yy.x * zz.x, -yy.x * zz.y };
    v2f u2 = (v2f){ -yy.y * zz.x,  yy.y * zz.y };
    v2f cu1 = (v2f){ u1.x, -u1.y };
    v2f cu2 = (v2f){ u2.x, -u2.y };
    v2f r1 = Ug2[2 * k], r2 = Ug2[2 * k + 1];
    v2f P1c = cmul(r1, u1);
    pkfma_bl_n(r2, cu2, P1c);
    pkfma_bh_mi(r2, cu2, P1c);
    v2f P2c = cmul(r1, u2);
    pkfma_bl(r2, cu1, P2c);
    pkfma_bh_i(r2, cu1, P2c);
    csW[wv][e][k] = make_float4(P1c.x, P1c.y, P2c.x, P2c.y);
  }
  __threadfence_block();

  // ---- per-lane constants ----
  const int a32 = (lane ^ 32) << 2;
  const int sb[6] = { (lane&32)<<26, (lane&16)<<27, (lane&8)<<28,
                      (lane&4)<<29, (lane&2)<<30, (lane&1)<<31 };
  const int addrA = ((lane ^ (lane >> 1)) & 63) << 2;
  const int addrB = addrA ^ 128;

  // ---- 4 states; build (init + layer-0 Rot folded), then ring 0 ----
  v2f S[4 * NE];
  #pragma unroll
  for (int e = 0; e < NE; ++e) build_state(&S[4*e], &csW[wv][e][0], lane);
  #pragma unroll
  for (int e = 0; e < NE; ++e) cnot_ring(&S[4*e], addrA, addrB, lane);

  // ---- layers 1,2; ring 1 explicit, ring 2 folded into readout ----
  #define LGB(l, i) { v2f P1 = Ug2[((l)*8+(i))*2], P2 = Ug2[((l)*8+(i))*2+1]; \
    gate_all<i>(S, P1, P2, sb, a32); }
  LGB(1,0) LGB(1,1) LGB(1,2) LGB(1,3) LGB(1,4) LGB(1,5) LGB(1,6) LGB(1,7)
  #pragma unroll
  for (int e = 0; e < NE; ++e) cnot_ring(&S[4*e], addrA, addrB, lane);
  LGB(2,0) LGB(2,1) LGB(2,2) LGB(2,3) LGB(2,4) LGB(2,5) LGB(2,6) LGB(2,7)
  #undef LGB

  // ---- readout + projection per element ----
  const int r0 = 2 * lane;
  const float4* wp = (const float4*)(Wp + r0 * 8);
  float4 w0v = wp[0], w1v = wp[1], w2v = wp[2], w3v = wp[3];
  float2 bpv = ((const float2*)bp)[lane];
  #pragma unroll
  for (int e = 0; e < NE; ++e) {
    float z[8];
    readout(&S[4*e], lane, sb, a32, z);
    float o0 = bpv.x + z[0]*w0v.x + z[1]*w0v.y + z[2]*w0v.z + z[3]*w0v.w
                     + z[4]*w1v.x + z[5]*w1v.y + z[6]*w1v.z + z[7]*w1v.w;
    float o1 = bpv.y + z[0]*w2v.x + z[1]*w2v.y + z[2]*w2v.z + z[3]*w2v.w
                     + z[4]*w3v.x + z[5]*w3v.y + z[6]*w3v.z + z[7]*w3v.w;
    ((float2*)(out + (size_t)(e0 + e) * 128))[lane] = make_float2(o0, o1);
  }
}

extern "C" void kernel_launch(void* const* d_in, const int* in_sizes, int n_in,
                              void* d_out, int out_size, void* d_ws, size_t ws_size,
                              hipStream_t stream) {
  const float* x  = (const float*)d_in[0];
  const float* W1 = (const float*)d_in[1];
  const float* b1 = (const float*)d_in[2];
  const float* W2 = (const float*)d_in[3];
  const float* b2 = (const float*)d_in[4];
  const float* W3 = (const float*)d_in[5];
  const float* b3 = (const float*)d_in[6];
  const float* qw = (const float*)d_in[7];
  const float* Wp = (const float*)d_in[8];
  const float* bp = (const float*)d_in[9];
  float* out = (float*)d_out;
  float* Urot = (float*)d_ws;

  const int B = in_sizes[0] / 80;
  const int B4 = B / NE;
  prep_rot_kernel<<<1, 64, 0, stream>>>(qw, Urot);
  const int grid = (B4 + WPB - 1) / WPB;
  qblock_kernel<<<grid, 64 * WPB, 0, stream>>>(x, W1, b1, W2, b2, W3, b3,
                                               Urot, Wp, bp, out, B4);
}

// Round 9
// 41.867 us; speedup vs baseline: 2.0654x; 1.0079x over previous
//
#include <hip/hip_runtime.h>

typedef float v2f __attribute__((ext_vector_type(2)));

#define WPB 4   // waves per block
#define NE  8   // batch elements per wave

__device__ __forceinline__ float xorf(float v, int sb) {
  return __int_as_float(__float_as_int(v) ^ sb);
}
__device__ __forceinline__ v2f xor2(v2f v, int sb) {
  return (v2f){xorf(v.x, sb), xorf(v.y, sb)};
}

// ---- VOP3P packed fp32 helpers; accumulating forms in-place (+v) --------
__device__ __forceinline__ void pkfma_ip(v2f a, v2f b, v2f& acc) {
  asm("v_pk_fma_f32 %0, %1, %2, %0" : "+v"(acc) : "v"(a), "v"(b));
}
__device__ __forceinline__ v2f pkmul_bl(v2f c, v2f v) {
  v2f r; asm("v_pk_mul_f32 %0, %1, %2 op_sel:[0,0] op_sel_hi:[0,1]"
             : "=v"(r) : "v"(c), "v"(v)); return r;
}
__device__ __forceinline__ void pkfma_bl(v2f c, v2f v, v2f& acc) {
  asm("v_pk_fma_f32 %0, %1, %2, %0 op_sel:[0,0,0] op_sel_hi:[0,1,1]"
      : "+v"(acc) : "v"(c), "v"(v));
}
__device__ __forceinline__ void pkfma_bl_n(v2f c, v2f v, v2f& acc) {
  asm("v_pk_fma_f32 %0, %1, %2, %0 op_sel:[0,0,0] op_sel_hi:[0,1,1] neg_lo:[1,0,0] neg_hi:[1,0,0]"
      : "+v"(acc) : "v"(c), "v"(v));
}
__device__ __forceinline__ void pkfma_bh_i(v2f c, v2f v, v2f& acc) {
  asm("v_pk_fma_f32 %0, %1, %2, %0 op_sel:[1,1,0] op_sel_hi:[1,0,1] neg_lo:[1,0,0]"
      : "+v"(acc) : "v"(c), "v"(v));
}
__device__ __forceinline__ void pkfma_bh_mi(v2f c, v2f v, v2f& acc) {
  asm("v_pk_fma_f32 %0, %1, %2, %0 op_sel:[1,1,0] op_sel_hi:[1,0,1] neg_hi:[1,0,0]"
      : "+v"(acc) : "v"(c), "v"(v));
}
__device__ __forceinline__ v2f cmul(v2f a, v2f b) {
  v2f r = pkmul_bl(a, b);
  pkfma_bh_i(a, b, r);
  return r;
}

// ---- cross-lane xor exchange (R6-verified prims) ------------------------
template<int M>
__device__ __forceinline__ float xch(float v, int a32) {
  if constexpr (M == 32)
    return __int_as_float(__builtin_amdgcn_ds_bpermute(a32, __float_as_int(v)));
  else if constexpr (M == 16 || M == 4)
    return __int_as_float(__builtin_amdgcn_ds_swizzle(__float_as_int(v), (M << 10) | 0x1f));
  else if constexpr (M == 8) {
    int i = __float_as_int(v);
    return __int_as_float(__builtin_amdgcn_update_dpp(i, i, 0x128, 0xF, 0xF, false));
  } else if constexpr (M == 2) {
    int i = __float_as_int(v);
    return __int_as_float(__builtin_amdgcn_update_dpp(i, i, 0x4E, 0xF, 0xF, false));
  } else {
    int i = __float_as_int(v);
    return __int_as_float(__builtin_amdgcn_update_dpp(i, i, 0xB1, 0xF, 0xF, false));
  }
}
template<int M>
__device__ __forceinline__ v2f xch2(v2f v, int a32) {
  v2f r; r.x = xch<M>(v.x, a32); r.y = xch<M>(v.y, a32); return r;
}
__device__ __forceinline__ v2f bperm2(int addr, v2f v) {
  v2f r;
  r.x = __int_as_float(__builtin_amdgcn_ds_bpermute(addr, __float_as_int(v.x)));
  r.y = __int_as_float(__builtin_amdgcn_ds_bpermute(addr, __float_as_int(v.y)));
  return r;
}

// ---- gate cores (R7-verified) -------------------------------------------
__device__ __forceinline__ void gpair(v2f& a, v2f& b, v2f P1, v2f P2) {
  v2f na = pkmul_bl(P1, a);
  pkfma_bh_i(P1, a, na);
  pkfma_bl(P2, b, na);
  pkfma_bh_i(P2, b, na);
  v2f nb = pkmul_bl(P1, b);
  pkfma_bh_mi(P1, b, nb);
  pkfma_bl_n(P2, a, nb);
  pkfma_bh_i(P2, a, nb);
  a = na; b = nb;
}
__device__ __forceinline__ v2f glane(v2f a, v2f p, v2f P1, v2f P2) {
  v2f t = pkmul_bl(P1, a);
  pkfma_bh_i(P1, a, t);
  pkfma_bl(P2, p, t);
  pkfma_bh_i(P2, p, t);
  return t;
}

// wire W on ALL NE elements' states; signed coeffs computed once
template<int W>
__device__ __forceinline__ void gate_all(v2f* S, v2f P1, v2f P2,
                                         const int* sb, int a32) {
  if constexpr (W == 0) {
    #pragma unroll
    for (int e = 0; e < NE; ++e) {
      gpair(S[4*e+0], S[4*e+2], P1, P2); gpair(S[4*e+1], S[4*e+3], P1, P2);
    }
  } else if constexpr (W == 1) {
    #pragma unroll
    for (int e = 0; e < NE; ++e) {
      gpair(S[4*e+0], S[4*e+1], P1, P2); gpair(S[4*e+2], S[4*e+3], P1, P2);
    }
  } else {
    constexpr int M = 1 << (7 - W);
    const int s = sb[W - 2];
    v2f P1s = P1; P1s.y = xorf(P1.y, s);
    v2f P2s = P2; P2s.x = xorf(P2.x, s);
    #pragma unroll
    for (int e = 0; e < NE; ++e) {
      v2f p0 = xch2<M>(S[4*e+0], a32), p1 = xch2<M>(S[4*e+1], a32),
          p2 = xch2<M>(S[4*e+2], a32), p3 = xch2<M>(S[4*e+3], a32);
      S[4*e+0] = glane(S[4*e+0], p0, P1s, P2s);
      S[4*e+1] = glane(S[4*e+1], p1, P1s, P2s);
      S[4*e+2] = glane(S[4*e+2], p2, P1s, P2s);
      S[4*e+3] = glane(S[4*e+3], p3, P1s, P2s);
    }
  }
}

// product-state build (init + layer-0 Rot folded)
__device__ __forceinline__ void build_state(v2f* S, const float4* csW, int lane) {
  v2f g[6];
  #pragma unroll
  for (int w = 2; w < 8; ++w) {
    float4 c = csW[w];
    v2f P1 = (v2f){c.x, c.y};
    v2f nc2 = (v2f){-c.z, c.w};
    bool shi = ((lane >> (7 - w)) & 1) != 0;
    g[w - 2] = shi ? nc2 : P1;
  }
  v2f c23 = cmul(g[0], g[1]);
  v2f c45 = cmul(g[2], g[3]);
  v2f c67 = cmul(g[4], g[5]);
  v2f common = cmul(c23, cmul(c45, c67));
  float4 c0 = csW[0], c1 = csW[1];
  v2f P10 = (v2f){c0.x, c0.y}, m0 = (v2f){-c0.z, c0.w};
  v2f P11 = (v2f){c1.x, c1.y}, m1 = (v2f){-c1.z, c1.w};
  S[0] = cmul(cmul(P10, P11), common);
  S[1] = cmul(cmul(P10, m1 ), common);
  S[2] = cmul(cmul(m0 , P11), common);
  S[3] = cmul(cmul(m0 , m1 ), common);
}

__device__ __forceinline__ void cnot_ring(v2f* S, int addrA, int addrB, int lane) {
  { v2f t = S[2]; S[2] = S[3]; S[3] = t; }
  S[0] = bperm2(addrA, S[0]); S[2] = bperm2(addrA, S[2]);
  S[1] = bperm2(addrB, S[1]); S[3] = bperm2(addrB, S[3]);
  bool c0 = (lane & 1) != 0;
  v2f t0 = S[0], t1 = S[1];
  S[0] = c0 ? S[2] : S[0]; S[2] = c0 ? t0 : S[2];
  S[1] = c0 ? S[3] : S[1]; S[3] = c0 ? t1 : S[3];
}

// paired readout: z[j] = ( z_j(elemA), z_j(elemB) ), ring-2 folded as signs
__device__ __forceinline__ void readout2(const v2f* SA, const v2f* SB,
                                         int lane, const int* sb, int a32, v2f* z) {
  v2f p0 = (v2f){fmaf(SA[0].x,SA[0].x,SA[0].y*SA[0].y), fmaf(SB[0].x,SB[0].x,SB[0].y*SB[0].y)};
  v2f p1 = (v2f){fmaf(SA[1].x,SA[1].x,SA[1].y*SA[1].y), fmaf(SB[1].x,SB[1].x,SB[1].y*SB[1].y)};
  v2f p2 = (v2f){fmaf(SA[2].x,SA[2].x,SA[2].y*SA[2].y), fmaf(SB[2].x,SB[2].x,SB[2].y*SB[2].y)};
  v2f p3 = (v2f){fmaf(SA[3].x,SA[3].x,SA[3].y*SA[3].y), fmaf(SB[3].x,SB[3].x,SB[3].y*SB[3].y)};
  v2f E = (p0 + p3) - (p1 + p2);
  v2f F = (p0 + p2) - (p1 + p3);
  v2f Fv = xor2(F, (__popc(lane) & 1) << 31);
  v2f Sm = E, d1, d2, d3, d4, d5, d6;
  { v2f p = xch2<32>(Sm, a32); d1 = xor2(Sm - p, sb[0]); Sm += p; }
  { v2f p = xch2<16>(Sm, a32); Sm += p;
    v2f q = xch2<16>(d1, a32); d2 = xor2(d1 - q, sb[1]); d1 += q; }
  { v2f p = xch2<8>(Sm, a32); Sm += p;
    v2f q = xch2<8>(d1, a32); d1 += q;
    v2f r = xch2<8>(d2, a32); d3 = xor2(d2 - r, sb[2]); d2 += r; }
  { v2f p = xch2<4>(Sm, a32); Sm += p;
    v2f q = xch2<4>(d1, a32); d1 += q;
    v2f r = xch2<4>(d2, a32); d2 += r;
    v2f t = xch2<4>(d3, a32); d4 = xor2(d3 - t, sb[3]); d3 += t; }
  { v2f p = xch2<2>(Sm, a32); Sm += p;
    v2f q = xch2<2>(d1, a32); d1 += q;
    v2f r = xch2<2>(d2, a32); d2 += r;
    v2f t = xch2<2>(d3, a32); d3 += t;
    v2f w = xch2<2>(d4, a32); d5 = xor2(d4 - w, sb[4]); d4 += w; }
  { v2f p = xch2<1>(Sm, a32); Sm += p;
    v2f q = xch2<1>(d1, a32); d1 += q;
    v2f r = xch2<1>(d2, a32); d2 += r;
    v2f t = xch2<1>(d3, a32); d3 += t;
    v2f w = xch2<1>(d4, a32); d4 += w;
    v2f v = xch2<1>(d5, a32); d6 = xor2(d5 - v, sb[5]); d5 += v; }
  Fv += xch2<32>(Fv, a32); Fv += xch2<16>(Fv, a32); Fv += xch2<8>(Fv, a32);
  Fv += xch2<4>(Fv, a32);  Fv += xch2<2>(Fv, a32);  Fv += xch2<1>(Fv, a32);
  z[0] = Fv; z[1] = Sm; z[2] = d1; z[3] = d2;
  z[4] = d3; z[5] = d4; z[6] = d5; z[7] = d6;
}

__device__ __forceinline__ float fast_tanh(float x) {
  float e = __expf(2.f * x);
  return 1.f - 2.f * __builtin_amdgcn_rcpf(e + 1.f);
}
__device__ __forceinline__ v2f vlo(float4 v) { return (v2f){v.x, v.y}; }
__device__ __forceinline__ v2f vhi(float4 v) { return (v2f){v.z, v.w}; }

__global__ void prep_rot_kernel(const float* __restrict__ qw, float* __restrict__ U) {
  int t = threadIdx.x;
  if (t < 24) {
    float phi = qw[t*3+0], theta = qw[t*3+1], omega = qw[t*3+2];
    float st, ct; sincosf(0.5f*theta, &st, &ct);
    float sa, ca; sincosf(0.5f*(phi+omega), &sa, &ca);
    float sd, cd; sincosf(0.5f*(phi-omega), &sd, &cd);
    float4 o; o.x = ct*ca; o.y = -ct*sa; o.z = -st*cd; o.w = -st*sd;
    ((float4*)U)[t] = o;
  }
}

__global__ __launch_bounds__(64*WPB) void qblock_kernel(
    const float* __restrict__ x,  const float* __restrict__ W1, const float* __restrict__ b1,
    const float* __restrict__ W2, const float* __restrict__ b2,
    const float* __restrict__ W3, const float* __restrict__ b3,
    const float* __restrict__ Urot, const float* __restrict__ Wp, const float* __restrict__ bp,
    float* __restrict__ out, int B8)
{
  __shared__ float  h1s[WPB][NE][64];
  __shared__ float  h2s[WPB][NE][32];
  __shared__ v2f    cs [WPB][NE][16];
  __shared__ float4 csW[WPB][NE][8];

  const int lane = threadIdx.x & 63;
  const int wv   = threadIdx.x >> 6;
  int bw = blockIdx.x * WPB + wv;
  if (bw >= B8) bw = B8 - 1;
  bw = __builtin_amdgcn_readfirstlane(bw);
  const int e0 = NE * bw;
  const v2f* Ug2 = (const v2f*)Urot;

  // ---- MLP layer 1: 80 -> 64 for 8 elements, shared weight loads ----
  {
    const float4* wr = (const float4*)(W1 + lane * 80);
    float bv = b1[lane];
    v2f a0[NE], a1[NE];
    #pragma unroll
    for (int e = 0; e < NE; ++e) { a0[e] = (v2f){bv, 0.f}; a1[e] = (v2f){0.f, 0.f}; }
    #pragma unroll
    for (int k = 0; k < 20; ++k) {
      float4 wk = wr[k];
      #pragma unroll
      for (int e = 0; e < NE; ++e) {
        float4 xk = ((const float4*)(x + (size_t)(e0 + e) * 80))[k];
        pkfma_ip(vlo(xk), vlo(wk), a0[e]);
        pkfma_ip(vhi(xk), vhi(wk), a1[e]);
      }
    }
    #pragma unroll
    for (int e = 0; e < NE; ++e)
      h1s[wv][e][lane] = fast_tanh((a0[e].x + a0[e].y) + (a1[e].x + a1[e].y));
  }
  __threadfence_block();

  // ---- layer 2: 64 -> 32; lane = (egrp, row): 4 elems per lane ----
  {
    const int eg = (lane >> 5) * 4, row = lane & 31;
    const float4* wr = (const float4*)(W2 + row * 64);
    v2f a0[4], a1[4];
    #pragma unroll
    for (int j = 0; j < 4; ++j) { a0[j] = (v2f){b2[row], 0.f}; a1[j] = (v2f){0.f, 0.f}; }
    #pragma unroll
    for (int k = 0; k < 16; ++k) {
      float4 wk = wr[k];
      #pragma unroll
      for (int j = 0; j < 4; ++j) {
        float4 hk = ((const float4*)(&h1s[wv][eg + j][0]))[k];
        pkfma_ip(vlo(hk), vlo(wk), a0[j]);
        pkfma_ip(vhi(hk), vhi(wk), a1[j]);
      }
    }
    #pragma unroll
    for (int j = 0; j < 4; ++j)
      h2s[wv][eg + j][row] = fast_tanh((a0[j].x + a0[j].y) + (a1[j].x + a1[j].y));
  }
  __threadfence_block();

  // ---- layer 3: 32 -> 16 angles; lane = (ebase, row): 2 elems per lane ----
  {
    const int eb = lane >> 4, row = lane & 15;
    const float4* wr = (const float4*)(W3 + row * 32);
    v2f a0[2], a1[2];
    #pragma unroll
    for (int j = 0; j < 2; ++j) { a0[j] = (v2f){b3[row], 0.f}; a1[j] = (v2f){0.f, 0.f}; }
    #pragma unroll
    for (int k = 0; k < 8; ++k) {
      float4 wk = wr[k];
      #pragma unroll
      for (int j = 0; j < 2; ++j) {
        float4 hk = ((const float4*)(&h2s[wv][eb + 4*j][0]))[k];
        pkfma_ip(vlo(hk), vlo(wk), a0[j]);
        pkfma_ip(vhi(hk), vhi(wk), a1[j]);
      }
    }
    #pragma unroll
    for (int j = 0; j < 2; ++j) {
      float sh, ch;
      __sincosf(0.5f * ((a0[j].x + a0[j].y) + (a1[j].x + a1[j].y)), &sh, &ch);
      cs[wv][eb + 4*j][row] = (v2f){ch, sh};
    }
  }
  __threadfence_block();

  // ---- combine W_i = Rot_l0_i . (RZ_i . RY_i): lane = (elem, wire) ----
  {
    const int e = lane >> 3, k = lane & 7;
    v2f yy = cs[wv][e][k], zz = cs[wv][e][k + 8];
    v2f u1 = (v2f){  yy.x * zz.x, -yy.x * zz.y };
    v2f u2 = (v2f){ -yy.y * zz.x,  yy.y * zz.y };
    v2f cu1 = (v2f){ u1.x, -u1.y };
    v2f cu2 = (v2f){ u2.x, -u2.y };
    v2f r1 = Ug2[2 * k], r2 = Ug2[2 * k + 1];
    v2f P1c = cmul(r1, u1);
    pkfma_bl_n(r2, cu2, P1c);
    pkfma_bh_mi(r2, cu2, P1c);
    v2f P2c = cmul(r1, u2);
    pkfma_bl(r2, cu1, P2c);
    pkfma_bh_i(r2, cu1, P2c);
    csW[wv][e][k] = make_float4(P1c.x, P1c.y, P2c.x, P2c.y);
  }
  __threadfence_block();

  // ---- per-lane constants ----
  const int a32 = (lane ^ 32) << 2;
  const int sb[6] = { (lane&32)<<26, (lane&16)<<27, (lane&8)<<28,
                      (lane&4)<<29, (lane&2)<<30, (lane&1)<<31 };
  const int addrA = ((lane ^ (lane >> 1)) & 63) << 2;
  const int addrB = addrA ^ 128;

  // ---- 8 states; build (init + layer-0 Rot folded), then ring 0 ----
  v2f S[4 * NE];
  #pragma unroll
  for (int e = 0; e < NE; ++e) build_state(&S[4*e], &csW[wv][e][0], lane);
  #pragma unroll
  for (int e = 0; e < NE; ++e) cnot_ring(&S[4*e], addrA, addrB, lane);

  // ---- layers 1,2; ring 1 explicit, ring 2 folded into readout ----
  #define LGB(l, i) { v2f P1 = Ug2[((l)*8+(i))*2], P2 = Ug2[((l)*8+(i))*2+1]; \
    gate_all<i>(S, P1, P2, sb, a32); }
  LGB(1,0) LGB(1,1) LGB(1,2) LGB(1,3) LGB(1,4) LGB(1,5) LGB(1,6) LGB(1,7)
  #pragma unroll
  for (int e = 0; e < NE; ++e) cnot_ring(&S[4*e], addrA, addrB, lane);
  LGB(2,0) LGB(2,1) LGB(2,2) LGB(2,3) LGB(2,4) LGB(2,5) LGB(2,6) LGB(2,7)
  #undef LGB

  // ---- paired readout + packed projection ----
  const int r0 = 2 * lane;
  const float4* wp = (const float4*)(Wp + r0 * 8);
  float4 w0v = wp[0], w1v = wp[1], w2v = wp[2], w3v = wp[3];
  float2 bpv = ((const float2*)bp)[lane];
  #pragma unroll
  for (int ep = 0; ep < NE / 2; ++ep) {
    v2f z[8];
    readout2(&S[8*ep], &S[8*ep + 4], lane, sb, a32, z);
    v2f o0 = (v2f){bpv.x, bpv.x};
    v2f o1 = (v2f){bpv.y, bpv.y};
    o0 += z[0]*w0v.x + z[1]*w0v.y + z[2]*w0v.z + z[3]*w0v.w
        + z[4]*w1v.x + z[5]*w1v.y + z[6]*w1v.z + z[7]*w1v.w;
    o1 += z[0]*w2v.x + z[1]*w2v.y + z[2]*w2v.z + z[3]*w2v.w
        + z[4]*w3v.x + z[5]*w3v.y + z[6]*w3v.z + z[7]*w3v.w;
    ((float2*)(out + (size_t)(e0 + 2*ep    ) * 128))[lane] = make_float2(o0.x, o1.x);
    ((float2*)(out + (size_t)(e0 + 2*ep + 1) * 128))[lane] = make_float2(o0.y, o1.y);
  }
}

extern "C" void kernel_launch(void* const* d_in, const int* in_sizes, int n_in,
                              void* d_out, int out_size, void* d_ws, size_t ws_size,
                              hipStream_t stream) {
  const float* x  = (const float*)d_in[0];
  const float* W1 = (const float*)d_in[1];
  const float* b1 = (const float*)d_in[2];
  const float* W2 = (const float*)d_in[3];
  const float* b2 = (const float*)d_in[4];
  const float* W3 = (const float*)d_in[5];
  const float* b3 = (const float*)d_in[6];
  const float* qw = (const float*)d_in[7];
  const float* Wp = (const float*)d_in[8];
  const float* bp = (const float*)d_in[9];
  float* out = (float*)d_out;
  float* Urot = (float*)d_ws;

  const int B = in_sizes[0] / 80;
  const int B8 = B / NE;
  prep_rot_kernel<<<1, 64, 0, stream>>>(qw, Urot);
  const int grid = (B8 + WPB - 1) / WPB;
  qblock_kernel<<<grid, 64 * WPB, 0, stream>>>(x, W1, b1, W2, b2, W3, b3,
                                               Urot, Wp, bp, out, B8);
}

// Round 10
// 41.861 us; speedup vs baseline: 2.0657x; 1.0001x over previous
//
#include <hip/hip_runtime.h>

typedef float v2f __attribute__((ext_vector_type(2)));

#define WPB 4   // waves per block
#define NE  4   // batch elements per wave

__device__ __forceinline__ float xorf(float v, int sb) {
  return __int_as_float(__float_as_int(v) ^ sb);
}
__device__ __forceinline__ v2f xor2(v2f v, int sb) {
  return (v2f){xorf(v.x, sb), xorf(v.y, sb)};
}

// ---- VOP3P packed fp32 helpers; accumulating forms in-place (+v) --------
__device__ __forceinline__ void pkfma_ip(v2f a, v2f b, v2f& acc) {
  asm("v_pk_fma_f32 %0, %1, %2, %0" : "+v"(acc) : "v"(a), "v"(b));
}
__device__ __forceinline__ v2f pkmul_bl(v2f c, v2f v) {
  v2f r; asm("v_pk_mul_f32 %0, %1, %2 op_sel:[0,0] op_sel_hi:[0,1]"
             : "=v"(r) : "v"(c), "v"(v)); return r;
}
__device__ __forceinline__ void pkfma_bl(v2f c, v2f v, v2f& acc) {
  asm("v_pk_fma_f32 %0, %1, %2, %0 op_sel:[0,0,0] op_sel_hi:[0,1,1]"
      : "+v"(acc) : "v"(c), "v"(v));
}
__device__ __forceinline__ void pkfma_bl_n(v2f c, v2f v, v2f& acc) {
  asm("v_pk_fma_f32 %0, %1, %2, %0 op_sel:[0,0,0] op_sel_hi:[0,1,1] neg_lo:[1,0,0] neg_hi:[1,0,0]"
      : "+v"(acc) : "v"(c), "v"(v));
}
__device__ __forceinline__ void pkfma_bh_i(v2f c, v2f v, v2f& acc) {
  asm("v_pk_fma_f32 %0, %1, %2, %0 op_sel:[1,1,0] op_sel_hi:[1,0,1] neg_lo:[1,0,0]"
      : "+v"(acc) : "v"(c), "v"(v));
}
__device__ __forceinline__ void pkfma_bh_mi(v2f c, v2f v, v2f& acc) {
  asm("v_pk_fma_f32 %0, %1, %2, %0 op_sel:[1,1,0] op_sel_hi:[1,0,1] neg_hi:[1,0,0]"
      : "+v"(acc) : "v"(c), "v"(v));
}
__device__ __forceinline__ v2f cmul(v2f a, v2f b) {
  v2f r = pkmul_bl(a, b);
  pkfma_bh_i(a, b, r);
  return r;
}

// ---- cross-lane xor exchange (R6-verified prims) ------------------------
template<int M>
__device__ __forceinline__ float xch(float v, int a32) {
  if constexpr (M == 32)
    return __int_as_float(__builtin_amdgcn_ds_bpermute(a32, __float_as_int(v)));
  else if constexpr (M == 16 || M == 4)
    return __int_as_float(__builtin_amdgcn_ds_swizzle(__float_as_int(v), (M << 10) | 0x1f));
  else if constexpr (M == 8) {
    int i = __float_as_int(v);
    return __int_as_float(__builtin_amdgcn_update_dpp(i, i, 0x128, 0xF, 0xF, false));
  } else if constexpr (M == 2) {
    int i = __float_as_int(v);
    return __int_as_float(__builtin_amdgcn_update_dpp(i, i, 0x4E, 0xF, 0xF, false));
  } else {
    int i = __float_as_int(v);
    return __int_as_float(__builtin_amdgcn_update_dpp(i, i, 0xB1, 0xF, 0xF, false));
  }
}
template<int M>
__device__ __forceinline__ v2f xch2(v2f v, int a32) {
  v2f r; r.x = xch<M>(v.x, a32); r.y = xch<M>(v.y, a32); return r;
}
__device__ __forceinline__ v2f bperm2(int addr, v2f v) {
  v2f r;
  r.x = __int_as_float(__builtin_amdgcn_ds_bpermute(addr, __float_as_int(v.x)));
  r.y = __int_as_float(__builtin_amdgcn_ds_bpermute(addr, __float_as_int(v.y)));
  return r;
}

// ---- gate cores (R7-verified) -------------------------------------------
__device__ __forceinline__ void gpair(v2f& a, v2f& b, v2f P1, v2f P2) {
  v2f na = pkmul_bl(P1, a);
  pkfma_bh_i(P1, a, na);
  pkfma_bl(P2, b, na);
  pkfma_bh_i(P2, b, na);
  v2f nb = pkmul_bl(P1, b);
  pkfma_bh_mi(P1, b, nb);
  pkfma_bl_n(P2, a, nb);
  pkfma_bh_i(P2, a, nb);
  a = na; b = nb;
}
__device__ __forceinline__ v2f glane(v2f a, v2f p, v2f P1, v2f P2) {
  v2f t = pkmul_bl(P1, a);
  pkfma_bh_i(P1, a, t);
  pkfma_bl(P2, p, t);
  pkfma_bh_i(P2, p, t);
  return t;
}

// wire W on ALL NE elements' states; signed coeffs computed once
template<int W>
__device__ __forceinline__ void gate_all(v2f* S, v2f P1, v2f P2,
                                         const int* sb, int a32) {
  if constexpr (W == 0) {
    #pragma unroll
    for (int e = 0; e < NE; ++e) {
      gpair(S[4*e+0], S[4*e+2], P1, P2); gpair(S[4*e+1], S[4*e+3], P1, P2);
    }
  } else if constexpr (W == 1) {
    #pragma unroll
    for (int e = 0; e < NE; ++e) {
      gpair(S[4*e+0], S[4*e+1], P1, P2); gpair(S[4*e+2], S[4*e+3], P1, P2);
    }
  } else {
    constexpr int M = 1 << (7 - W);
    const int s = sb[W - 2];
    v2f P1s = P1; P1s.y = xorf(P1.y, s);
    v2f P2s = P2; P2s.x = xorf(P2.x, s);
    #pragma unroll
    for (int e = 0; e < NE; ++e) {
      v2f p0 = xch2<M>(S[4*e+0], a32), p1 = xch2<M>(S[4*e+1], a32),
          p2 = xch2<M>(S[4*e+2], a32), p3 = xch2<M>(S[4*e+3], a32);
      S[4*e+0] = glane(S[4*e+0], p0, P1s, P2s);
      S[4*e+1] = glane(S[4*e+1], p1, P1s, P2s);
      S[4*e+2] = glane(S[4*e+2], p2, P1s, P2s);
      S[4*e+3] = glane(S[4*e+3], p3, P1s, P2s);
    }
  }
}

// product-state build (init + layer-0 Rot folded)
__device__ __forceinline__ void build_state(v2f* S, const float4* csW, int lane) {
  v2f g[6];
  #pragma unroll
  for (int w = 2; w < 8; ++w) {
    float4 c = csW[w];
    v2f P1 = (v2f){c.x, c.y};
    v2f nc2 = (v2f){-c.z, c.w};
    bool shi = ((lane >> (7 - w)) & 1) != 0;
    g[w - 2] = shi ? nc2 : P1;
  }
  v2f c23 = cmul(g[0], g[1]);
  v2f c45 = cmul(g[2], g[3]);
  v2f c67 = cmul(g[4], g[5]);
  v2f common = cmul(c23, cmul(c45, c67));
  float4 c0 = csW[0], c1 = csW[1];
  v2f P10 = (v2f){c0.x, c0.y}, m0 = (v2f){-c0.z, c0.w};
  v2f P11 = (v2f){c1.x, c1.y}, m1 = (v2f){-c1.z, c1.w};
  S[0] = cmul(cmul(P10, P11), common);
  S[1] = cmul(cmul(P10, m1 ), common);
  S[2] = cmul(cmul(m0 , P11), common);
  S[3] = cmul(cmul(m0 , m1 ), common);
}

__device__ __forceinline__ void cnot_ring(v2f* S, int addrA, int addrB, int lane) {
  { v2f t = S[2]; S[2] = S[3]; S[3] = t; }
  S[0] = bperm2(addrA, S[0]); S[2] = bperm2(addrA, S[2]);
  S[1] = bperm2(addrB, S[1]); S[3] = bperm2(addrB, S[3]);
  bool c0 = (lane & 1) != 0;
  v2f t0 = S[0], t1 = S[1];
  S[0] = c0 ? S[2] : S[0]; S[2] = c0 ? t0 : S[2];
  S[1] = c0 ? S[3] : S[1]; S[3] = c0 ? t1 : S[3];
}

// paired readout: z[j] = ( z_j(elemA), z_j(elemB) ), ring-2 folded as signs
__device__ __forceinline__ void readout2(const v2f* SA, const v2f* SB,
                                         int lane, const int* sb, int a32, v2f* z) {
  v2f p0 = (v2f){fmaf(SA[0].x,SA[0].x,SA[0].y*SA[0].y), fmaf(SB[0].x,SB[0].x,SB[0].y*SB[0].y)};
  v2f p1 = (v2f){fmaf(SA[1].x,SA[1].x,SA[1].y*SA[1].y), fmaf(SB[1].x,SB[1].x,SB[1].y*SB[1].y)};
  v2f p2 = (v2f){fmaf(SA[2].x,SA[2].x,SA[2].y*SA[2].y), fmaf(SB[2].x,SB[2].x,SB[2].y*SB[2].y)};
  v2f p3 = (v2f){fmaf(SA[3].x,SA[3].x,SA[3].y*SA[3].y), fmaf(SB[3].x,SB[3].x,SB[3].y*SB[3].y)};
  v2f E = (p0 + p3) - (p1 + p2);
  v2f F = (p0 + p2) - (p1 + p3);
  v2f Fv = xor2(F, (__popc(lane) & 1) << 31);
  v2f Sm = E, d1, d2, d3, d4, d5, d6;
  { v2f p = xch2<32>(Sm, a32); d1 = xor2(Sm - p, sb[0]); Sm += p; }
  { v2f p = xch2<16>(Sm, a32); Sm += p;
    v2f q = xch2<16>(d1, a32); d2 = xor2(d1 - q, sb[1]); d1 += q; }
  { v2f p = xch2<8>(Sm, a32); Sm += p;
    v2f q = xch2<8>(d1, a32); d1 += q;
    v2f r = xch2<8>(d2, a32); d3 = xor2(d2 - r, sb[2]); d2 += r; }
  { v2f p = xch2<4>(Sm, a32); Sm += p;
    v2f q = xch2<4>(d1, a32); d1 += q;
    v2f r = xch2<4>(d2, a32); d2 += r;
    v2f t = xch2<4>(d3, a32); d4 = xor2(d3 - t, sb[3]); d3 += t; }
  { v2f p = xch2<2>(Sm, a32); Sm += p;
    v2f q = xch2<2>(d1, a32); d1 += q;
    v2f r = xch2<2>(d2, a32); d2 += r;
    v2f t = xch2<2>(d3, a32); d3 += t;
    v2f w = xch2<2>(d4, a32); d5 = xor2(d4 - w, sb[4]); d4 += w; }
  { v2f p = xch2<1>(Sm, a32); Sm += p;
    v2f q = xch2<1>(d1, a32); d1 += q;
    v2f r = xch2<1>(d2, a32); d2 += r;
    v2f t = xch2<1>(d3, a32); d3 += t;
    v2f w = xch2<1>(d4, a32); d4 += w;
    v2f v = xch2<1>(d5, a32); d6 = xor2(d5 - v, sb[5]); d5 += v; }
  Fv += xch2<32>(Fv, a32); Fv += xch2<16>(Fv, a32); Fv += xch2<8>(Fv, a32);
  Fv += xch2<4>(Fv, a32);  Fv += xch2<2>(Fv, a32);  Fv += xch2<1>(Fv, a32);
  z[0] = Fv; z[1] = Sm; z[2] = d1; z[3] = d2;
  z[4] = d3; z[5] = d4; z[6] = d5; z[7] = d6;
}

__device__ __forceinline__ float fast_tanh(float x) {
  float e = __expf(2.f * x);
  return 1.f - 2.f * __builtin_amdgcn_rcpf(e + 1.f);
}
__device__ __forceinline__ v2f vlo(float4 v) { return (v2f){v.x, v.y}; }
__device__ __forceinline__ v2f vhi(float4 v) { return (v2f){v.z, v.w}; }

__global__ void prep_rot_kernel(const float* __restrict__ qw, float* __restrict__ U) {
  int t = threadIdx.x;
  if (t < 24) {
    float phi = qw[t*3+0], theta = qw[t*3+1], omega = qw[t*3+2];
    float st, ct; sincosf(0.5f*theta, &st, &ct);
    float sa, ca; sincosf(0.5f*(phi+omega), &sa, &ca);
    float sd, cd; sincosf(0.5f*(phi-omega), &sd, &cd);
    float4 o; o.x = ct*ca; o.y = -ct*sa; o.z = -st*cd; o.w = -st*sd;
    ((float4*)U)[t] = o;
  }
}

// 4 waves/SIMD min -> VGPR budget 128: fits the 32-float state array, no spill
__global__ __launch_bounds__(64*WPB, 4) void qblock_kernel(
    const float* __restrict__ x,  const float* __restrict__ W1, const float* __restrict__ b1,
    const float* __restrict__ W2, const float* __restrict__ b2,
    const float* __restrict__ W3, const float* __restrict__ b3,
    const float* __restrict__ Urot, const float* __restrict__ Wp, const float* __restrict__ bp,
    float* __restrict__ out, int B4)
{
  __shared__ float  h1s[WPB][NE][64];
  __shared__ float  h2s[WPB][NE][32];
  __shared__ v2f    cs [WPB][NE][16];
  __shared__ float4 csW[WPB][NE][8];

  const int lane = threadIdx.x & 63;
  const int wv   = threadIdx.x >> 6;
  int bw = blockIdx.x * WPB + wv;
  if (bw >= B4) bw = B4 - 1;
  bw = __builtin_amdgcn_readfirstlane(bw);
  const int e0 = NE * bw;
  const v2f* Ug2 = (const v2f*)Urot;

  // ---- MLP layer 1: 80 -> 64 for 4 elements, shared weight loads ----
  {
    const float4* wr = (const float4*)(W1 + lane * 80);
    float bv = b1[lane];
    v2f a0[NE], a1[NE];
    #pragma unroll
    for (int e = 0; e < NE; ++e) { a0[e] = (v2f){bv, 0.f}; a1[e] = (v2f){0.f, 0.f}; }
    #pragma unroll
    for (int k = 0; k < 20; ++k) {
      float4 wk = wr[k];
      #pragma unroll
      for (int e = 0; e < NE; ++e) {
        float4 xk = ((const float4*)(x + (size_t)(e0 + e) * 80))[k];
        pkfma_ip(vlo(xk), vlo(wk), a0[e]);
        pkfma_ip(vhi(xk), vhi(wk), a1[e]);
      }
    }
    #pragma unroll
    for (int e = 0; e < NE; ++e)
      h1s[wv][e][lane] = fast_tanh((a0[e].x + a0[e].y) + (a1[e].x + a1[e].y));
  }
  __threadfence_block();

  // ---- layer 2: 64 -> 32; lane = (epair, row): 2 elems per lane ----
  {
    const int ep = lane >> 5, row = lane & 31;
    const float4* wr = (const float4*)(W2 + row * 64);
    const float4* hvA = (const float4*)(&h1s[wv][2*ep+0][0]);
    const float4* hvB = (const float4*)(&h1s[wv][2*ep+1][0]);
    v2f aA0 = (v2f){b2[row], 0.f}, aA1 = (v2f){0.f, 0.f};
    v2f aB0 = aA0, aB1 = aA1;
    #pragma unroll
    for (int k = 0; k < 16; ++k) {
      float4 wk = wr[k], hA = hvA[k], hB = hvB[k];
      pkfma_ip(vlo(hA), vlo(wk), aA0); pkfma_ip(vhi(hA), vhi(wk), aA1);
      pkfma_ip(vlo(hB), vlo(wk), aB0); pkfma_ip(vhi(hB), vhi(wk), aB1);
    }
    h2s[wv][2*ep+0][row] = fast_tanh((aA0.x + aA0.y) + (aA1.x + aA1.y));
    h2s[wv][2*ep+1][row] = fast_tanh((aB0.x + aB0.y) + (aB1.x + aB1.y));
  }
  __threadfence_block();

  // ---- layer 3: 32 -> 16 angles; lane = (elem, row), all 64 lanes ----
  {
    const int e = lane >> 4, row = lane & 15;
    const float4* hv = (const float4*)(&h2s[wv][e][0]);
    const float4* wr = (const float4*)(W3 + row * 32);
    v2f ac0 = (v2f){b3[row], 0.f}, ac1 = (v2f){0.f, 0.f};
    #pragma unroll
    for (int k = 0; k < 8; ++k) {
      float4 hk = hv[k], wk = wr[k];
      pkfma_ip(vlo(hk), vlo(wk), ac0);
      pkfma_ip(vhi(hk), vhi(wk), ac1);
    }
    float sh, ch; __sincosf(0.5f * ((ac0.x + ac0.y) + (ac1.x + ac1.y)), &sh, &ch);
    cs[wv][e][row] = (v2f){ch, sh};
  }
  __threadfence_block();

  // ---- combine W_i = Rot_l0_i . (RZ_i . RY_i): lane = (elem, wire), 32 lanes ----
  if (lane < 32) {
    const int e = lane >> 3, k = lane & 7;
    v2f yy = cs[wv][e][k], zz = cs[wv][e][k + 8];
    v2f u1 = (v2f){  yy.x * zz.x, -yy.x * zz.y };
    v2f u2 = (v2f){ -yy.y * zz.x,  yy.y * zz.y };
    v2f cu1 = (v2f){ u1.x, -u1.y };
    v2f cu2 = (v2f){ u2.x, -u2.y };
    v2f r1 = Ug2[2 * k], r2 = Ug2[2 * k + 1];
    v2f P1c = cmul(r1, u1);
    pkfma_bl_n(r2, cu2, P1c);
    pkfma_bh_mi(r2, cu2, P1c);
    v2f P2c = cmul(r1, u2);
    pkfma_bl(r2, cu1, P2c);
    pkfma_bh_i(r2, cu1, P2c);
    csW[wv][e][k] = make_float4(P1c.x, P1c.y, P2c.x, P2c.y);
  }
  __threadfence_block();

  // ---- per-lane constants ----
  const int a32 = (lane ^ 32) << 2;
  const int sb[6] = { (lane&32)<<26, (lane&16)<<27, (lane&8)<<28,
                      (lane&4)<<29, (lane&2)<<30, (lane&1)<<31 };
  const int addrA = ((lane ^ (lane >> 1)) & 63) << 2;
  const int addrB = addrA ^ 128;

  // ---- 4 states; build (init + layer-0 Rot folded), then ring 0 ----
  v2f S[4 * NE];
  #pragma unroll
  for (int e = 0; e < NE; ++e) build_state(&S[4*e], &csW[wv][e][0], lane);
  #pragma unroll
  for (int e = 0; e < NE; ++e) cnot_ring(&S[4*e], addrA, addrB, lane);

  // ---- layers 1,2; ring 1 explicit, ring 2 folded into readout ----
  #define LGB(l, i) { v2f P1 = Ug2[((l)*8+(i))*2], P2 = Ug2[((l)*8+(i))*2+1]; \
    gate_all<i>(S, P1, P2, sb, a32); }
  LGB(1,0) LGB(1,1) LGB(1,2) LGB(1,3) LGB(1,4) LGB(1,5) LGB(1,6) LGB(1,7)
  #pragma unroll
  for (int e = 0; e < NE; ++e) cnot_ring(&S[4*e], addrA, addrB, lane);
  LGB(2,0) LGB(2,1) LGB(2,2) LGB(2,3) LGB(2,4) LGB(2,5) LGB(2,6) LGB(2,7)
  #undef LGB

  // ---- paired readout + packed projection ----
  const int r0 = 2 * lane;
  const float4* wp = (const float4*)(Wp + r0 * 8);
  float4 w0v = wp[0], w1v = wp[1], w2v = wp[2], w3v = wp[3];
  float2 bpv = ((const float2*)bp)[lane];
  #pragma unroll
  for (int ep = 0; ep < NE / 2; ++ep) {
    v2f z[8];
    readout2(&S[8*ep], &S[8*ep + 4], lane, sb, a32, z);
    v2f o0 = (v2f){bpv.x, bpv.x};
    v2f o1 = (v2f){bpv.y, bpv.y};
    o0 += z[0]*w0v.x + z[1]*w0v.y + z[2]*w0v.z + z[3]*w0v.w
        + z[4]*w1v.x + z[5]*w1v.y + z[6]*w1v.z + z[7]*w1v.w;
    o1 += z[0]*w2v.x + z[1]*w2v.y + z[2]*w2v.z + z[3]*w2v.w
        + z[4]*w3v.x + z[5]*w3v.y + z[6]*w3v.z + z[7]*w3v.w;
    ((float2*)(out + (size_t)(e0 + 2*ep    ) * 128))[lane] = make_float2(o0.x, o1.x);
    ((float2*)(out + (size_t)(e0 + 2*ep + 1) * 128))[lane] = make_float2(o0.y, o1.y);
  }
}

extern "C" void kernel_launch(void* const* d_in, const int* in_sizes, int n_in,
                              void* d_out, int out_size, void* d_ws, size_t ws_size,
                              hipStream_t stream) {
  const float* x  = (const float*)d_in[0];
  const float* W1 = (const float*)d_in[1];
  const float* b1 = (const float*)d_in[2];
  const float* W2 = (const float*)d_in[3];
  const float* b2 = (const float*)d_in[4];
  const float* W3 = (const float*)d_in[5];
  const float* b3 = (const float*)d_in[6];
  const float* qw = (const float*)d_in[7];
  const float* Wp = (const float*)d_in[8];
  const float* bp = (const float*)d_in[9];
  float* out = (float*)d_out;
  float* Urot = (float*)d_ws;

  const int B = in_sizes[0] / 80;
  const int B4 = B / NE;
  prep_rot_kernel<<<1, 64, 0, stream>>>(qw, Urot);
  const int grid = (B4 + WPB - 1) / WPB;
  qblock_kernel<<<grid, 64 * WPB, 0, stream>>>(x, W1, b1, W2, b2, W3, b3,
                                               Urot, Wp, bp, out, B4);
}

// Round 12
// 41.792 us; speedup vs baseline: 2.0691x; 1.0016x over previous
//
#include <hip/hip_runtime.h>

typedef float v2f __attribute__((ext_vector_type(2)));

#define WPB 4   // waves per block
#define NE  4   // batch elements per wave

__device__ __forceinline__ float xorf(float v, int sb) {
  return __int_as_float(__float_as_int(v) ^ sb);
}
__device__ __forceinline__ v2f xor2(v2f v, int sb) {
  return (v2f){xorf(v.x, sb), xorf(v.y, sb)};
}

// ---- VOP3P packed fp32 helpers; accumulating forms in-place (+v) --------
__device__ __forceinline__ void pkfma_ip(v2f a, v2f b, v2f& acc) {
  asm("v_pk_fma_f32 %0, %1, %2, %0" : "+v"(acc) : "v"(a), "v"(b));
}
__device__ __forceinline__ v2f pkmul_bl(v2f c, v2f v) {
  v2f r; asm("v_pk_mul_f32 %0, %1, %2 op_sel:[0,0] op_sel_hi:[0,1]"
             : "=v"(r) : "v"(c), "v"(v)); return r;
}
__device__ __forceinline__ void pkfma_bl(v2f c, v2f v, v2f& acc) {
  asm("v_pk_fma_f32 %0, %1, %2, %0 op_sel:[0,0,0] op_sel_hi:[0,1,1]"
      : "+v"(acc) : "v"(c), "v"(v));
}
__device__ __forceinline__ void pkfma_bl_n(v2f c, v2f v, v2f& acc) {
  asm("v_pk_fma_f32 %0, %1, %2, %0 op_sel:[0,0,0] op_sel_hi:[0,1,1] neg_lo:[1,0,0] neg_hi:[1,0,0]"
      : "+v"(acc) : "v"(c), "v"(v));
}
__device__ __forceinline__ void pkfma_bh_i(v2f c, v2f v, v2f& acc) {
  asm("v_pk_fma_f32 %0, %1, %2, %0 op_sel:[1,1,0] op_sel_hi:[1,0,1] neg_lo:[1,0,0]"
      : "+v"(acc) : "v"(c), "v"(v));
}
__device__ __forceinline__ void pkfma_bh_mi(v2f c, v2f v, v2f& acc) {
  asm("v_pk_fma_f32 %0, %1, %2, %0 op_sel:[1,1,0] op_sel_hi:[1,0,1] neg_hi:[1,0,0]"
      : "+v"(acc) : "v"(c), "v"(v));
}
__device__ __forceinline__ v2f cmul(v2f a, v2f b) {
  v2f r = pkmul_bl(a, b);
  pkfma_bh_i(a, b, r);
  return r;
}

// ---- cross-lane xor exchange (R6-verified prims) ------------------------
template<int M>
__device__ __forceinline__ float xch(float v, int a32) {
  if constexpr (M == 32)
    return __int_as_float(__builtin_amdgcn_ds_bpermute(a32, __float_as_int(v)));
  else if constexpr (M == 16 || M == 4)
    return __int_as_float(__builtin_amdgcn_ds_swizzle(__float_as_int(v), (M << 10) | 0x1f));
  else if constexpr (M == 8) {
    int i = __float_as_int(v);
    return __int_as_float(__builtin_amdgcn_update_dpp(i, i, 0x128, 0xF, 0xF, false));
  } else if constexpr (M == 2) {
    int i = __float_as_int(v);
    return __int_as_float(__builtin_amdgcn_update_dpp(i, i, 0x4E, 0xF, 0xF, false));
  } else {
    int i = __float_as_int(v);
    return __int_as_float(__builtin_amdgcn_update_dpp(i, i, 0xB1, 0xF, 0xF, false));
  }
}
template<int M>
__device__ __forceinline__ v2f xch2(v2f v, int a32) {
  v2f r; r.x = xch<M>(v.x, a32); r.y = xch<M>(v.y, a32); return r;
}
__device__ __forceinline__ v2f bperm2(int addr, v2f v) {
  v2f r;
  r.x = __int_as_float(__builtin_amdgcn_ds_bpermute(addr, __float_as_int(v.x)));
  r.y = __int_as_float(__builtin_amdgcn_ds_bpermute(addr, __float_as_int(v.y)));
  return r;
}

// ---- gate cores (R7-verified) -------------------------------------------
__device__ __forceinline__ void gpair(v2f& a, v2f& b, v2f P1, v2f P2) {
  v2f na = pkmul_bl(P1, a);
  pkfma_bh_i(P1, a, na);
  pkfma_bl(P2, b, na);
  pkfma_bh_i(P2, b, na);
  v2f nb = pkmul_bl(P1, b);
  pkfma_bh_mi(P1, b, nb);
  pkfma_bl_n(P2, a, nb);
  pkfma_bh_i(P2, a, nb);
  a = na; b = nb;
}
__device__ __forceinline__ v2f glane(v2f a, v2f p, v2f P1, v2f P2) {
  v2f t = pkmul_bl(P1, a);
  pkfma_bh_i(P1, a, t);
  pkfma_bl(P2, p, t);
  pkfma_bh_i(P2, p, t);
  return t;
}

// wire W on one element's 4 NAMED state regs
template<int W>
__device__ __forceinline__ void gate_elem(v2f& S0, v2f& S1, v2f& S2, v2f& S3,
                                          v2f P1, v2f P2, int a32) {
  if constexpr (W == 0)      { gpair(S0, S2, P1, P2); gpair(S1, S3, P1, P2); }
  else if constexpr (W == 1) { gpair(S0, S1, P1, P2); gpair(S2, S3, P1, P2); }
  else {
    constexpr int M = 1 << (7 - W);
    v2f p0 = xch2<M>(S0, a32), p1 = xch2<M>(S1, a32),
        p2 = xch2<M>(S2, a32), p3 = xch2<M>(S3, a32);
    S0 = glane(S0, p0, P1, P2); S1 = glane(S1, p1, P1, P2);
    S2 = glane(S2, p2, P1, P2); S3 = glane(S3, p3, P1, P2);
  }
}

// product-state build (init + layer-0 Rot folded) into named regs
__device__ __forceinline__ void build_state(v2f& S0, v2f& S1, v2f& S2, v2f& S3,
                                            const float4* csW, int lane) {
  v2f g2, g3, g4, g5, g6, g7;
  #define BG(q, dst) { float4 c = csW[q]; \
    v2f P1 = (v2f){c.x, c.y}; v2f nc2 = (v2f){-c.z, c.w}; \
    dst = (((lane >> (7 - (q))) & 1) != 0) ? nc2 : P1; }
  BG(2, g2) BG(3, g3) BG(4, g4) BG(5, g5) BG(6, g6) BG(7, g7)
  #undef BG
  v2f common = cmul(cmul(cmul(g2, g3), cmul(g4, g5)), cmul(g6, g7));
  float4 c0 = csW[0], c1 = csW[1];
  v2f P10 = (v2f){c0.x, c0.y}, m0 = (v2f){-c0.z, c0.w};
  v2f P11 = (v2f){c1.x, c1.y}, m1 = (v2f){-c1.z, c1.w};
  S0 = cmul(cmul(P10, P11), common);
  S1 = cmul(cmul(P10, m1 ), common);
  S2 = cmul(cmul(m0 , P11), common);
  S3 = cmul(cmul(m0 , m1 ), common);
}

__device__ __forceinline__ void cnot_ring(v2f& S0, v2f& S1, v2f& S2, v2f& S3,
                                          int addrA, int addrB, int lane) {
  { v2f t = S2; S2 = S3; S3 = t; }
  S0 = bperm2(addrA, S0); S2 = bperm2(addrA, S2);
  S1 = bperm2(addrB, S1); S3 = bperm2(addrB, S3);
  bool c0 = (lane & 1) != 0;
  v2f t0 = S0, t1 = S1;
  S0 = c0 ? S2 : S0; S2 = c0 ? t0 : S2;
  S1 = c0 ? S3 : S1; S3 = c0 ? t1 : S3;
}

// paired readout into NAMED z regs; ring-2 folded as parity signs
__device__ __forceinline__ void readout2(v2f A0, v2f A1, v2f A2, v2f A3,
                                         v2f B0, v2f B1, v2f B2, v2f B3,
                                         int lane, const int* sb, int a32,
                                         v2f& z0, v2f& z1, v2f& z2, v2f& z3,
                                         v2f& z4, v2f& z5, v2f& z6, v2f& z7) {
  v2f p0 = (v2f){fmaf(A0.x,A0.x,A0.y*A0.y), fmaf(B0.x,B0.x,B0.y*B0.y)};
  v2f p1 = (v2f){fmaf(A1.x,A1.x,A1.y*A1.y), fmaf(B1.x,B1.x,B1.y*B1.y)};
  v2f p2 = (v2f){fmaf(A2.x,A2.x,A2.y*A2.y), fmaf(B2.x,B2.x,B2.y*B2.y)};
  v2f p3 = (v2f){fmaf(A3.x,A3.x,A3.y*A3.y), fmaf(B3.x,B3.x,B3.y*B3.y)};
  v2f E = (p0 + p3) - (p1 + p2);
  v2f F = (p0 + p2) - (p1 + p3);
  v2f Fv = xor2(F, (__popc(lane) & 1) << 31);
  v2f Sm = E, d1, d2, d3, d4, d5, d6;
  { v2f p = xch2<32>(Sm, a32); d1 = xor2(Sm - p, sb[0]); Sm += p; }
  { v2f p = xch2<16>(Sm, a32); Sm += p;
    v2f q = xch2<16>(d1, a32); d2 = xor2(d1 - q, sb[1]); d1 += q; }
  { v2f p = xch2<8>(Sm, a32); Sm += p;
    v2f q = xch2<8>(d1, a32); d1 += q;
    v2f r = xch2<8>(d2, a32); d3 = xor2(d2 - r, sb[2]); d2 += r; }
  { v2f p = xch2<4>(Sm, a32); Sm += p;
    v2f q = xch2<4>(d1, a32); d1 += q;
    v2f r = xch2<4>(d2, a32); d2 += r;
    v2f t = xch2<4>(d3, a32); d4 = xor2(d3 - t, sb[3]); d3 += t; }
  { v2f p = xch2<2>(Sm, a32); Sm += p;
    v2f q = xch2<2>(d1, a32); d1 += q;
    v2f r = xch2<2>(d2, a32); d2 += r;
    v2f t = xch2<2>(d3, a32); d3 += t;
    v2f w = xch2<2>(d4, a32); d5 = xor2(d4 - w, sb[4]); d4 += w; }
  { v2f p = xch2<1>(Sm, a32); Sm += p;
    v2f q = xch2<1>(d1, a32); d1 += q;
    v2f r = xch2<1>(d2, a32); d2 += r;
    v2f t = xch2<1>(d3, a32); d3 += t;
    v2f w = xch2<1>(d4, a32); d4 += w;
    v2f v = xch2<1>(d5, a32); d6 = xor2(d5 - v, sb[5]); d5 += v; }
  Fv += xch2<32>(Fv, a32); Fv += xch2<16>(Fv, a32); Fv += xch2<8>(Fv, a32);
  Fv += xch2<4>(Fv, a32);  Fv += xch2<2>(Fv, a32);  Fv += xch2<1>(Fv, a32);
  z0 = Fv; z1 = Sm; z2 = d1; z3 = d2;
  z4 = d3; z5 = d4; z6 = d5; z7 = d6;
}

__device__ __forceinline__ float fast_tanh(float x) {
  float e = __expf(2.f * x);
  return 1.f - 2.f * __builtin_amdgcn_rcpf(e + 1.f);
}
__device__ __forceinline__ v2f vlo(float4 v) { return (v2f){v.x, v.y}; }
__device__ __forceinline__ v2f vhi(float4 v) { return (v2f){v.z, v.w}; }

__global__ void prep_rot_kernel(const float* __restrict__ qw, float* __restrict__ U) {
  int t = threadIdx.x;
  if (t < 24) {
    float phi = qw[t*3+0], theta = qw[t*3+1], omega = qw[t*3+2];
    float st, ct; sincosf(0.5f*theta, &st, &ct);
    float sa, ca; sincosf(0.5f*(phi+omega), &sa, &ca);
    float sd, cd; sincosf(0.5f*(phi-omega), &sd, &cd);
    float4 o; o.x = ct*ca; o.y = -ct*sa; o.z = -st*cd; o.w = -st*sd;
    ((float4*)U)[t] = o;
  }
}

__global__ __launch_bounds__(64*WPB, 4) void qblock_kernel(
    const float* __restrict__ x,  const float* __restrict__ W1, const float* __restrict__ b1,
    const float* __restrict__ W2, const float* __restrict__ b2,
    const float* __restrict__ W3, const float* __restrict__ b3,
    const float* __restrict__ Urot, const float* __restrict__ Wp, const float* __restrict__ bp,
    float* __restrict__ out, int B4)
{
  __shared__ float  h1s[WPB][NE][64];
  __shared__ float  h2s[WPB][NE][32];
  __shared__ v2f    cs [WPB][NE][16];
  __shared__ float4 csW[WPB][NE][8];

  const int lane = threadIdx.x & 63;
  const int wv   = threadIdx.x >> 6;
  int bw = blockIdx.x * WPB + wv;
  if (bw >= B4) bw = B4 - 1;
  bw = __builtin_amdgcn_readfirstlane(bw);
  const int e0 = NE * bw;
  const v2f* Ug2 = (const v2f*)Urot;

  // ---- MLP layer 1: 80 -> 64 for 4 elements, named accumulators ----
  {
    const float4* wr = (const float4*)(W1 + lane * 80);
    float bv = b1[lane];
    v2f a0A = (v2f){bv,0.f}, a1A = (v2f){0.f,0.f};
    v2f a0B = a0A, a1B = a1A, a0C = a0A, a1C = a1A, a0D = a0A, a1D = a1A;
    #pragma unroll
    for (int k = 0; k < 20; ++k) {
      float4 wk = wr[k];
      #define L1E(E, e) { \
        float4 xk = ((const float4*)(x + (size_t)(e0 + (e)) * 80))[k]; \
        pkfma_ip(vlo(xk), vlo(wk), a0##E); pkfma_ip(vhi(xk), vhi(wk), a1##E); }
      L1E(A,0) L1E(B,1) L1E(C,2) L1E(D,3)
      #undef L1E
    }
    h1s[wv][0][lane] = fast_tanh((a0A.x + a0A.y) + (a1A.x + a1A.y));
    h1s[wv][1][lane] = fast_tanh((a0B.x + a0B.y) + (a1B.x + a1B.y));
    h1s[wv][2][lane] = fast_tanh((a0C.x + a0C.y) + (a1C.x + a1C.y));
    h1s[wv][3][lane] = fast_tanh((a0D.x + a0D.y) + (a1D.x + a1D.y));
  }
  __threadfence_block();

  // ---- layer 2: 64 -> 32; lane = (epair, row): 2 elems per lane ----
  {
    const int ep = lane >> 5, row = lane & 31;
    const float4* wr = (const float4*)(W2 + row * 64);
    const float4* hvA = (const float4*)(&h1s[wv][2*ep+0][0]);
    const float4* hvB = (const float4*)(&h1s[wv][2*ep+1][0]);
    v2f aA0 = (v2f){b2[row], 0.f}, aA1 = (v2f){0.f, 0.f};
    v2f aB0 = aA0, aB1 = aA1;
    #pragma unroll
    for (int k = 0; k < 16; ++k) {
      float4 wk = wr[k], hA = hvA[k], hB = hvB[k];
      pkfma_ip(vlo(hA), vlo(wk), aA0); pkfma_ip(vhi(hA), vhi(wk), aA1);
      pkfma_ip(vlo(hB), vlo(wk), aB0); pkfma_ip(vhi(hB), vhi(wk), aB1);
    }
    h2s[wv][2*ep+0][row] = fast_tanh((aA0.x + aA0.y) + (aA1.x + aA1.y));
    h2s[wv][2*ep+1][row] = fast_tanh((aB0.x + aB0.y) + (aB1.x + aB1.y));
  }
  __threadfence_block();

  // ---- layer 3: 32 -> 16 angles; lane = (elem, row), all 64 lanes ----
  {
    const int e = lane >> 4, row = lane & 15;
    const float4* hv = (const float4*)(&h2s[wv][e][0]);
    const float4* wr = (const float4*)(W3 + row * 32);
    v2f ac0 = (v2f){b3[row], 0.f}, ac1 = (v2f){0.f, 0.f};
    #pragma unroll
    for (int k = 0; k < 8; ++k) {
      float4 hk = hv[k], wk = wr[k];
      pkfma_ip(vlo(hk), vlo(wk), ac0);
      pkfma_ip(vhi(hk), vhi(wk), ac1);
    }
    float sh, ch; __sincosf(0.5f * ((ac0.x + ac0.y) + (ac1.x + ac1.y)), &sh, &ch);
    cs[wv][e][row] = (v2f){ch, sh};
  }
  __threadfence_block();

  // ---- combine W_i = Rot_l0_i . (RZ_i . RY_i): lane = (elem, wire), 32 lanes ----
  if (lane < 32) {
    const int e = lane >> 3, k = lane & 7;
    v2f yy = cs[wv][e][k], zz = cs[wv][e][k + 8];
    v2f u1 = (v2f){  yy.x * zz.x, -yy.x * zz.y };
    v2f u2 = (v2f){ -yy.y * zz.x,  yy.y * zz.y };
    v2f cu1 = (v2f){ u1.x, -u1.y };
    v2f cu2 = (v2f){ u2.x, -u2.y };
    v2f r1 = Ug2[2 * k], r2 = Ug2[2 * k + 1];
    v2f P1c = cmul(r1, u1);
    pkfma_bl_n(r2, cu2, P1c);
    pkfma_bh_mi(r2, cu2, P1c);
    v2f P2c = cmul(r1, u2);
    pkfma_bl(r2, cu1, P2c);
    pkfma_bh_i(r2, cu1, P2c);
    csW[wv][e][k] = make_float4(P1c.x, P1c.y, P2c.x, P2c.y);
  }
  __threadfence_block();

  // ---- per-lane constants ----
  const int a32 = (lane ^ 32) << 2;
  const int sb[6] = { (lane&32)<<26, (lane&16)<<27, (lane&8)<<28,
                      (lane&4)<<29, (lane&2)<<30, (lane&1)<<31 };
  const int addrA = ((lane ^ (lane >> 1)) & 63) << 2;
  const int addrB = addrA ^ 128;

  // ---- 4 states in 16 NAMED regs; build, then ring 0 ----
  v2f sA0, sA1, sA2, sA3, sB0, sB1, sB2, sB3;
  v2f sC0, sC1, sC2, sC3, sD0, sD1, sD2, sD3;
  build_state(sA0, sA1, sA2, sA3, &csW[wv][0][0], lane);
  build_state(sB0, sB1, sB2, sB3, &csW[wv][1][0], lane);
  build_state(sC0, sC1, sC2, sC3, &csW[wv][2][0], lane);
  build_state(sD0, sD1, sD2, sD3, &csW[wv][3][0], lane);
  #define RING_ALL \
    cnot_ring(sA0, sA1, sA2, sA3, addrA, addrB, lane); \
    cnot_ring(sB0, sB1, sB2, sB3, addrA, addrB, lane); \
    cnot_ring(sC0, sC1, sC2, sC3, addrA, addrB, lane); \
    cnot_ring(sD0, sD1, sD2, sD3, addrA, addrB, lane);
  RING_ALL

  // ---- layers 1,2; ring 1 explicit, ring 2 folded into readout ----
  #define LG(l, i) { \
    v2f P1 = Ug2[((l)*8+(i))*2], P2 = Ug2[((l)*8+(i))*2+1]; \
    if constexpr ((i) >= 2) { \
      P1.y = xorf(P1.y, sb[(i)-2]); P2.x = xorf(P2.x, sb[(i)-2]); } \
    gate_elem<i>(sA0, sA1, sA2, sA3, P1, P2, a32); \
    gate_elem<i>(sB0, sB1, sB2, sB3, P1, P2, a32); \
    gate_elem<i>(sC0, sC1, sC2, sC3, P1, P2, a32); \
    gate_elem<i>(sD0, sD1, sD2, sD3, P1, P2, a32); }
  LG(1,0) LG(1,1) LG(1,2) LG(1,3) LG(1,4) LG(1,5) LG(1,6) LG(1,7)
  RING_ALL
  LG(2,0) LG(2,1) LG(2,2) LG(2,3) LG(2,4) LG(2,5) LG(2,6) LG(2,7)
  #undef LG
  #undef RING_ALL

  // ---- paired readout + packed projection ----
  const int r0 = 2 * lane;
  const float4* wp = (const float4*)(Wp + r0 * 8);
  float4 w0v = wp[0], w1v = wp[1], w2v = wp[2], w3v = wp[3];
  float2 bpv = ((const float2*)bp)[lane];
  #define PROJ_STORE(eA, eB) { \
    v2f o0 = (v2f){bpv.x, bpv.x}; \
    v2f o1 = (v2f){bpv.y, bpv.y}; \
    o0 += z0*w0v.x + z1*w0v.y + z2*w0v.z + z3*w0v.w \
        + z4*w1v.x + z5*w1v.y + z6*w1v.z + z7*w1v.w; \
    o1 += z0*w2v.x + z1*w2v.y + z2*w2v.z + z3*w2v.w \
        + z4*w3v.x + z5*w3v.y + z6*w3v.z + z7*w3v.w; \
    ((float2*)(out + (size_t)(e0 + (eA)) * 128))[lane] = make_float2(o0.x, o1.x); \
    ((float2*)(out + (size_t)(e0 + (eB)) * 128))[lane] = make_float2(o0.y, o1.y); }
  {
    v2f z0, z1, z2, z3, z4, z5, z6, z7;
    readout2(sA0, sA1, sA2, sA3, sB0, sB1, sB2, sB3, lane, sb, a32,
             z0, z1, z2, z3, z4, z5, z6, z7);
    PROJ_STORE(0, 1)
  }
  {
    v2f z0, z1, z2, z3, z4, z5, z6, z7;
    readout2(sC0, sC1, sC2, sC3, sD0, sD1, sD2, sD3, lane, sb, a32,
             z0, z1, z2, z3, z4, z5, z6, z7);
    PROJ_STORE(2, 3)
  }
  #undef PROJ_STORE
}

extern "C" void kernel_launch(void* const* d_in, const int* in_sizes, int n_in,
                              void* d_out, int out_size, void* d_ws, size_t ws_size,
                              hipStream_t stream) {
  const float* x  = (const float*)d_in[0];
  const float* W1 = (const float*)d_in[1];
  const float* b1 = (const float*)d_in[2];
  const float* W2 = (const float*)d_in[3];
  const float* b2 = (const float*)d_in[4];
  const float* W3 = (const float*)d_in[5];
  const float* b3 = (const float*)d_in[6];
  const float* qw = (const float*)d_in[7];
  const float* Wp = (const float*)d_in[8];
  const float* bp = (const float*)d_in[9];
  float* out = (float*)d_out;
  float* Urot = (float*)d_ws;

  const int B = in_sizes[0] / 80;
  const int B4 = B / NE;
  prep_rot_kernel<<<1, 64, 0, stream>>>(qw, Urot);
  const int grid = (B4 + WPB - 1) / WPB;
  qblock_kernel<<<grid, 64 * WPB, 0, stream>>>(x, W1, b1, W2, b2, W3, b3,
                                               Urot, Wp, bp, out, B4);
}

// Round 13
// 41.392 us; speedup vs baseline: 2.0891x; 1.0097x over previous
//
#include <hip/hip_runtime.h>

typedef float v2f __attribute__((ext_vector_type(2)));

#define WPB 4   // waves per block
#define NE  4   // batch elements per wave

__device__ __forceinline__ float xorf(float v, int sb) {
  return __int_as_float(__float_as_int(v) ^ sb);
}
__device__ __forceinline__ v2f xor2(v2f v, int sb) {
  return (v2f){xorf(v.x, sb), xorf(v.y, sb)};
}

// ---- VOP3P packed fp32 helpers; accumulating forms in-place (+v) --------
__device__ __forceinline__ void pkfma_ip(v2f a, v2f b, v2f& acc) {
  asm("v_pk_fma_f32 %0, %1, %2, %0" : "+v"(acc) : "v"(a), "v"(b));
}
__device__ __forceinline__ v2f pkmul_bl(v2f c, v2f v) {
  v2f r; asm("v_pk_mul_f32 %0, %1, %2 op_sel:[0,0] op_sel_hi:[0,1]"
             : "=v"(r) : "v"(c), "v"(v)); return r;
}
__device__ __forceinline__ void pkfma_bl(v2f c, v2f v, v2f& acc) {
  asm("v_pk_fma_f32 %0, %1, %2, %0 op_sel:[0,0,0] op_sel_hi:[0,1,1]"
      : "+v"(acc) : "v"(c), "v"(v));
}
__device__ __forceinline__ void pkfma_bl_n(v2f c, v2f v, v2f& acc) {
  asm("v_pk_fma_f32 %0, %1, %2, %0 op_sel:[0,0,0] op_sel_hi:[0,1,1] neg_lo:[1,0,0] neg_hi:[1,0,0]"
      : "+v"(acc) : "v"(c), "v"(v));
}
__device__ __forceinline__ void pkfma_bh_i(v2f c, v2f v, v2f& acc) {
  asm("v_pk_fma_f32 %0, %1, %2, %0 op_sel:[1,1,0] op_sel_hi:[1,0,1] neg_lo:[1,0,0]"
      : "+v"(acc) : "v"(c), "v"(v));
}
__device__ __forceinline__ void pkfma_bh_mi(v2f c, v2f v, v2f& acc) {
  asm("v_pk_fma_f32 %0, %1, %2, %0 op_sel:[1,1,0] op_sel_hi:[1,0,1] neg_hi:[1,0,0]"
      : "+v"(acc) : "v"(c), "v"(v));
}
__device__ __forceinline__ v2f cmul(v2f a, v2f b) {
  v2f r = pkmul_bl(a, b);
  pkfma_bh_i(a, b, r);
  return r;
}

// ---- cross-lane xor exchange (R6-verified prims) ------------------------
template<int M>
__device__ __forceinline__ float xch(float v, int a32) {
  if constexpr (M == 32)
    return __int_as_float(__builtin_amdgcn_ds_bpermute(a32, __float_as_int(v)));
  else if constexpr (M == 16 || M == 4)
    return __int_as_float(__builtin_amdgcn_ds_swizzle(__float_as_int(v), (M << 10) | 0x1f));
  else if constexpr (M == 8) {
    int i = __float_as_int(v);
    return __int_as_float(__builtin_amdgcn_update_dpp(i, i, 0x128, 0xF, 0xF, false));
  } else if constexpr (M == 2) {
    int i = __float_as_int(v);
    return __int_as_float(__builtin_amdgcn_update_dpp(i, i, 0x4E, 0xF, 0xF, false));
  } else {
    int i = __float_as_int(v);
    return __int_as_float(__builtin_amdgcn_update_dpp(i, i, 0xB1, 0xF, 0xF, false));
  }
}
template<int M>
__device__ __forceinline__ v2f xch2(v2f v, int a32) {
  v2f r; r.x = xch<M>(v.x, a32); r.y = xch<M>(v.y, a32); return r;
}
__device__ __forceinline__ v2f bperm2(int addr, v2f v) {
  v2f r;
  r.x = __int_as_float(__builtin_amdgcn_ds_bpermute(addr, __float_as_int(v.x)));
  r.y = __int_as_float(__builtin_amdgcn_ds_bpermute(addr, __float_as_int(v.y)));
  return r;
}

// ---- gate cores (R7-verified) -------------------------------------------
__device__ __forceinline__ void gpair(v2f& a, v2f& b, v2f P1, v2f P2) {
  v2f na = pkmul_bl(P1, a);
  pkfma_bh_i(P1, a, na);
  pkfma_bl(P2, b, na);
  pkfma_bh_i(P2, b, na);
  v2f nb = pkmul_bl(P1, b);
  pkfma_bh_mi(P1, b, nb);
  pkfma_bl_n(P2, a, nb);
  pkfma_bh_i(P2, a, nb);
  a = na; b = nb;
}
__device__ __forceinline__ v2f glane(v2f a, v2f p, v2f P1, v2f P2) {
  v2f t = pkmul_bl(P1, a);
  pkfma_bh_i(P1, a, t);
  pkfma_bl(P2, p, t);
  pkfma_bh_i(P2, p, t);
  return t;
}

// product-state build (init + layer-0 Rot folded) into named regs
__device__ __forceinline__ void build_state(v2f& S0, v2f& S1, v2f& S2, v2f& S3,
                                            const float4* csW, int lane) {
  v2f g2, g3, g4, g5, g6, g7;
  #define BG(q, dst) { float4 c = csW[q]; \
    v2f P1 = (v2f){c.x, c.y}; v2f nc2 = (v2f){-c.z, c.w}; \
    dst = (((lane >> (7 - (q))) & 1) != 0) ? nc2 : P1; }
  BG(2, g2) BG(3, g3) BG(4, g4) BG(5, g5) BG(6, g6) BG(7, g7)
  #undef BG
  v2f common = cmul(cmul(cmul(g2, g3), cmul(g4, g5)), cmul(g6, g7));
  float4 c0 = csW[0], c1 = csW[1];
  v2f P10 = (v2f){c0.x, c0.y}, m0 = (v2f){-c0.z, c0.w};
  v2f P11 = (v2f){c1.x, c1.y}, m1 = (v2f){-c1.z, c1.w};
  S0 = cmul(cmul(P10, P11), common);
  S1 = cmul(cmul(P10, m1 ), common);
  S2 = cmul(cmul(m0 , P11), common);
  S3 = cmul(cmul(m0 , m1 ), common);
}

__device__ __forceinline__ float fast_tanh(float x) {
  float e = __expf(2.f * x);
  return 1.f - 2.f * __builtin_amdgcn_rcpf(e + 1.f);
}
__device__ __forceinline__ v2f vlo(float4 v) { return (v2f){v.x, v.y}; }
__device__ __forceinline__ v2f vhi(float4 v) { return (v2f){v.z, v.w}; }

__global__ void prep_rot_kernel(const float* __restrict__ qw, float* __restrict__ U) {
  int t = threadIdx.x;
  if (t < 24) {
    float phi = qw[t*3+0], theta = qw[t*3+1], omega = qw[t*3+2];
    float st, ct; sincosf(0.5f*theta, &st, &ct);
    float sa, ca; sincosf(0.5f*(phi+omega), &sa, &ca);
    float sd, cd; sincosf(0.5f*(phi-omega), &sd, &cd);
    float4 o; o.x = ct*ca; o.y = -ct*sa; o.z = -st*cd; o.w = -st*sd;
    ((float4*)U)[t] = o;
  }
}

__global__ __launch_bounds__(64*WPB, 4) void qblock_kernel(
    const float* __restrict__ x,  const float* __restrict__ W1, const float* __restrict__ b1,
    const float* __restrict__ W2, const float* __restrict__ b2,
    const float* __restrict__ W3, const float* __restrict__ b3,
    const float* __restrict__ Urot, const float* __restrict__ Wp, const float* __restrict__ bp,
    float* __restrict__ out, int B4)
{
  __shared__ float  h1s[WPB][NE][64];
  __shared__ float  h2s[WPB][NE][32];
  __shared__ v2f    cs [WPB][NE][16];
  __shared__ float4 csW[WPB][NE][8];

  const int lane = threadIdx.x & 63;
  const int wv   = threadIdx.x >> 6;
  int bw = blockIdx.x * WPB + wv;
  if (bw >= B4) bw = B4 - 1;
  bw = __builtin_amdgcn_readfirstlane(bw);
  const int e0 = NE * bw;
  const v2f* Ug2 = (const v2f*)Urot;

  // ---- MLP layer 1: 80 -> 64 for 4 elements, named accumulators ----
  {
    const float4* wr = (const float4*)(W1 + lane * 80);
    float bv = b1[lane];
    v2f a0A = (v2f){bv,0.f}, a1A = (v2f){0.f,0.f};
    v2f a0B = a0A, a1B = a1A, a0C = a0A, a1C = a1A, a0D = a0A, a1D = a1A;
    #pragma unroll
    for (int k = 0; k < 20; ++k) {
      float4 wk = wr[k];
      #define L1E(E, e) { \
        float4 xk = ((const float4*)(x + (size_t)(e0 + (e)) * 80))[k]; \
        pkfma_ip(vlo(xk), vlo(wk), a0##E); pkfma_ip(vhi(xk), vhi(wk), a1##E); }
      L1E(A,0) L1E(B,1) L1E(C,2) L1E(D,3)
      #undef L1E
    }
    h1s[wv][0][lane] = fast_tanh((a0A.x + a0A.y) + (a1A.x + a1A.y));
    h1s[wv][1][lane] = fast_tanh((a0B.x + a0B.y) + (a1B.x + a1B.y));
    h1s[wv][2][lane] = fast_tanh((a0C.x + a0C.y) + (a1C.x + a1C.y));
    h1s[wv][3][lane] = fast_tanh((a0D.x + a0D.y) + (a1D.x + a1D.y));
  }
  __threadfence_block();

  // ---- layer 2: 64 -> 32; lane = (epair, row): 2 elems per lane ----
  {
    const int ep = lane >> 5, row = lane & 31;
    const float4* wr = (const float4*)(W2 + row * 64);
    const float4* hvA = (const float4*)(&h1s[wv][2*ep+0][0]);
    const float4* hvB = (const float4*)(&h1s[wv][2*ep+1][0]);
    v2f aA0 = (v2f){b2[row], 0.f}, aA1 = (v2f){0.f, 0.f};
    v2f aB0 = aA0, aB1 = aA1;
    #pragma unroll
    for (int k = 0; k < 16; ++k) {
      float4 wk = wr[k], hA = hvA[k], hB = hvB[k];
      pkfma_ip(vlo(hA), vlo(wk), aA0); pkfma_ip(vhi(hA), vhi(wk), aA1);
      pkfma_ip(vlo(hB), vlo(wk), aB0); pkfma_ip(vhi(hB), vhi(wk), aB1);
    }
    h2s[wv][2*ep+0][row] = fast_tanh((aA0.x + aA0.y) + (aA1.x + aA1.y));
    h2s[wv][2*ep+1][row] = fast_tanh((aB0.x + aB0.y) + (aB1.x + aB1.y));
  }
  __threadfence_block();

  // ---- layer 3: 32 -> 16 angles; lane = (elem, row), all 64 lanes ----
  {
    const int e = lane >> 4, row = lane & 15;
    const float4* hv = (const float4*)(&h2s[wv][e][0]);
    const float4* wr = (const float4*)(W3 + row * 32);
    v2f ac0 = (v2f){b3[row], 0.f}, ac1 = (v2f){0.f, 0.f};
    #pragma unroll
    for (int k = 0; k < 8; ++k) {
      float4 hk = hv[k], wk = wr[k];
      pkfma_ip(vlo(hk), vlo(wk), ac0);
      pkfma_ip(vhi(hk), vhi(wk), ac1);
    }
    float sh, ch; __sincosf(0.5f * ((ac0.x + ac0.y) + (ac1.x + ac1.y)), &sh, &ch);
    cs[wv][e][row] = (v2f){ch, sh};
  }
  __threadfence_block();

  // ---- combine W_i = Rot_l0_i . (RZ_i . RY_i): lane = (elem, wire), 32 lanes ----
  if (lane < 32) {
    const int e = lane >> 3, k = lane & 7;
    v2f yy = cs[wv][e][k], zz = cs[wv][e][k + 8];
    v2f u1 = (v2f){  yy.x * zz.x, -yy.x * zz.y };
    v2f u2 = (v2f){ -yy.y * zz.x,  yy.y * zz.y };
    v2f cu1 = (v2f){ u1.x, -u1.y };
    v2f cu2 = (v2f){ u2.x, -u2.y };
    v2f r1 = Ug2[2 * k], r2 = Ug2[2 * k + 1];
    v2f P1c = cmul(r1, u1);
    pkfma_bl_n(r2, cu2, P1c);
    pkfma_bh_mi(r2, cu2, P1c);
    v2f P2c = cmul(r1, u2);
    pkfma_bl(r2, cu1, P2c);
    pkfma_bh_i(r2, cu1, P2c);
    csW[wv][e][k] = make_float4(P1c.x, P1c.y, P2c.x, P2c.y);
  }
  __threadfence_block();

  // ---- per-lane constants ----
  const int a32 = (lane ^ 32) << 2;
  const int sb[6] = { (lane&32)<<26, (lane&16)<<27, (lane&8)<<28,
                      (lane&4)<<29, (lane&2)<<30, (lane&1)<<31 };
  const int addrA = ((lane ^ (lane >> 1)) & 63) << 2;
  const int addrB = addrA ^ 128;

  // ---- 4 states in 16 NAMED regs ----
  v2f sA0, sA1, sA2, sA3, sB0, sB1, sB2, sB3;
  v2f sC0, sC1, sC2, sC3, sD0, sD1, sD2, sD3;
  build_state(sA0, sA1, sA2, sA3, &csW[wv][0][0], lane);
  build_state(sB0, sB1, sB2, sB3, &csW[wv][1][0], lane);
  build_state(sC0, sC1, sC2, sC3, &csW[wv][2][0], lane);
  build_state(sD0, sD1, sD2, sD3, &csW[wv][3][0], lane);

  // interleaved CNOT ring: all 16 bpermutes issued back-to-back, then selects
  #define RING_ALL { \
    v2f t; \
    t = sA2; sA2 = sA3; sA3 = t;  t = sB2; sB2 = sB3; sB3 = t; \
    t = sC2; sC2 = sC3; sC3 = t;  t = sD2; sD2 = sD3; sD3 = t; \
    v2f qA0 = bperm2(addrA, sA0), qA2 = bperm2(addrA, sA2), \
        qA1 = bperm2(addrB, sA1), qA3 = bperm2(addrB, sA3), \
        qB0 = bperm2(addrA, sB0), qB2 = bperm2(addrA, sB2), \
        qB1 = bperm2(addrB, sB1), qB3 = bperm2(addrB, sB3), \
        qC0 = bperm2(addrA, sC0), qC2 = bperm2(addrA, sC2), \
        qC1 = bperm2(addrB, sC1), qC3 = bperm2(addrB, sC3), \
        qD0 = bperm2(addrA, sD0), qD2 = bperm2(addrA, sD2), \
        qD1 = bperm2(addrB, sD1), qD3 = bperm2(addrB, sD3); \
    bool c0 = (lane & 1) != 0; \
    sA0 = c0 ? qA2 : qA0; sA2 = c0 ? qA0 : qA2; \
    sA1 = c0 ? qA3 : qA1; sA3 = c0 ? qA1 : qA3; \
    sB0 = c0 ? qB2 : qB0; sB2 = c0 ? qB0 : qB2; \
    sB1 = c0 ? qB3 : qB1; sB3 = c0 ? qB1 : qB3; \
    sC0 = c0 ? qC2 : qC0; sC2 = c0 ? qC0 : qC2; \
    sC1 = c0 ? qC3 : qC1; sC3 = c0 ? qC1 : qC3; \
    sD0 = c0 ? qD2 : qD0; sD2 = c0 ? qD0 : qD2; \
    sD1 = c0 ? qD3 : qD1; sD3 = c0 ? qD1 : qD3; }
  RING_ALL

  // wires 0,1: register-pair gates (no exchange)
  #define LG01(l, i) { \
    v2f P1 = Ug2[((l)*8+(i))*2], P2 = Ug2[((l)*8+(i))*2+1]; \
    if constexpr ((i) == 0) { \
      gpair(sA0, sA2, P1, P2); gpair(sA1, sA3, P1, P2); \
      gpair(sB0, sB2, P1, P2); gpair(sB1, sB3, P1, P2); \
      gpair(sC0, sC2, P1, P2); gpair(sC1, sC3, P1, P2); \
      gpair(sD0, sD2, P1, P2); gpair(sD1, sD3, P1, P2); \
    } else { \
      gpair(sA0, sA1, P1, P2); gpair(sA2, sA3, P1, P2); \
      gpair(sB0, sB1, P1, P2); gpair(sB2, sB3, P1, P2); \
      gpair(sC0, sC1, P1, P2); gpair(sC2, sC3, P1, P2); \
      gpair(sD0, sD1, P1, P2); gpair(sD2, sD3, P1, P2); } }

  // wires 2..7: ALL 16 exchanges issued first, then 16 dependent gate ops
  #define LGX(l, i) { \
    v2f P1 = Ug2[((l)*8+(i))*2], P2 = Ug2[((l)*8+(i))*2+1]; \
    P1.y = xorf(P1.y, sb[(i)-2]); P2.x = xorf(P2.x, sb[(i)-2]); \
    v2f pA0 = xch2<(1<<(7-(i)))>(sA0, a32), pA1 = xch2<(1<<(7-(i)))>(sA1, a32), \
        pA2 = xch2<(1<<(7-(i)))>(sA2, a32), pA3 = xch2<(1<<(7-(i)))>(sA3, a32), \
        pB0 = xch2<(1<<(7-(i)))>(sB0, a32), pB1 = xch2<(1<<(7-(i)))>(sB1, a32), \
        pB2 = xch2<(1<<(7-(i)))>(sB2, a32), pB3 = xch2<(1<<(7-(i)))>(sB3, a32), \
        pC0 = xch2<(1<<(7-(i)))>(sC0, a32), pC1 = xch2<(1<<(7-(i)))>(sC1, a32), \
        pC2 = xch2<(1<<(7-(i)))>(sC2, a32), pC3 = xch2<(1<<(7-(i)))>(sC3, a32), \
        pD0 = xch2<(1<<(7-(i)))>(sD0, a32), pD1 = xch2<(1<<(7-(i)))>(sD1, a32), \
        pD2 = xch2<(1<<(7-(i)))>(sD2, a32), pD3 = xch2<(1<<(7-(i)))>(sD3, a32); \
    sA0 = glane(sA0, pA0, P1, P2); sA1 = glane(sA1, pA1, P1, P2); \
    sA2 = glane(sA2, pA2, P1, P2); sA3 = glane(sA3, pA3, P1, P2); \
    sB0 = glane(sB0, pB0, P1, P2); sB1 = glane(sB1, pB1, P1, P2); \
    sB2 = glane(sB2, pB2, P1, P2); sB3 = glane(sB3, pB3, P1, P2); \
    sC0 = glane(sC0, pC0, P1, P2); sC1 = glane(sC1, pC1, P1, P2); \
    sC2 = glane(sC2, pC2, P1, P2); sC3 = glane(sC3, pC3, P1, P2); \
    sD0 = glane(sD0, pD0, P1, P2); sD1 = glane(sD1, pD1, P1, P2); \
    sD2 = glane(sD2, pD2, P1, P2); sD3 = glane(sD3, pD3, P1, P2); }

  LG01(1,0) LG01(1,1) LGX(1,2) LGX(1,3) LGX(1,4) LGX(1,5) LGX(1,6) LGX(1,7)
  RING_ALL
  LG01(2,0) LG01(2,1) LGX(2,2) LGX(2,3) LGX(2,4) LGX(2,5) LGX(2,6) LGX(2,7)
  #undef LG01
  #undef LGX
  #undef RING_ALL

  // ---- interleaved readout for 4 elements (pair-groups u=(A,B), w=(C,D)) ----
  v2f zu0,zu1,zu2,zu3,zu4,zu5,zu6,zu7;
  v2f zw0,zw1,zw2,zw3,zw4,zw5,zw6,zw7;
  {
    v2f pu0 = (v2f){fmaf(sA0.x,sA0.x,sA0.y*sA0.y), fmaf(sB0.x,sB0.x,sB0.y*sB0.y)};
    v2f pu1 = (v2f){fmaf(sA1.x,sA1.x,sA1.y*sA1.y), fmaf(sB1.x,sB1.x,sB1.y*sB1.y)};
    v2f pu2 = (v2f){fmaf(sA2.x,sA2.x,sA2.y*sA2.y), fmaf(sB2.x,sB2.x,sB2.y*sB2.y)};
    v2f pu3 = (v2f){fmaf(sA3.x,sA3.x,sA3.y*sA3.y), fmaf(sB3.x,sB3.x,sB3.y*sB3.y)};
    v2f pw0 = (v2f){fmaf(sC0.x,sC0.x,sC0.y*sC0.y), fmaf(sD0.x,sD0.x,sD0.y*sD0.y)};
    v2f pw1 = (v2f){fmaf(sC1.x,sC1.x,sC1.y*sC1.y), fmaf(sD1.x,sD1.x,sD1.y*sD1.y)};
    v2f pw2 = (v2f){fmaf(sC2.x,sC2.x,sC2.y*sC2.y), fmaf(sD2.x,sD2.x,sD2.y*sD2.y)};
    v2f pw3 = (v2f){fmaf(sC3.x,sC3.x,sC3.y*sC3.y), fmaf(sD3.x,sD3.x,sD3.y*sD3.y)};
    v2f Eu = (pu0 + pu3) - (pu1 + pu2), Fu = (pu0 + pu2) - (pu1 + pu3);
    v2f Ew = (pw0 + pw3) - (pw1 + pw2), Fw = (pw0 + pw2) - (pw1 + pw3);
    const int pl = (__popc(lane) & 1) << 31;
    v2f Fvu = xor2(Fu, pl), Fvw = xor2(Fw, pl);
    v2f Smu = Eu, Smw = Ew;
    v2f d1u, d2u, d3u, d4u, d5u, d6u, d1w, d2w, d3w, d4w, d5w, d6w;
    { v2f pu = xch2<32>(Smu, a32); v2f pw = xch2<32>(Smw, a32);
      d1u = xor2(Smu - pu, sb[0]); Smu += pu;
      d1w = xor2(Smw - pw, sb[0]); Smw += pw; }
    { v2f pu = xch2<16>(Smu, a32), qu = xch2<16>(d1u, a32);
      v2f pw = xch2<16>(Smw, a32), qw = xch2<16>(d1w, a32);
      Smu += pu; d2u = xor2(d1u - qu, sb[1]); d1u += qu;
      Smw += pw; d2w = xor2(d1w - qw, sb[1]); d1w += qw; }
    { v2f pu = xch2<8>(Smu, a32), qu = xch2<8>(d1u, a32), ru = xch2<8>(d2u, a32);
      v2f pw = xch2<8>(Smw, a32), qw = xch2<8>(d1w, a32), rw = xch2<8>(d2w, a32);
      Smu += pu; d1u += qu; d3u = xor2(d2u - ru, sb[2]); d2u += ru;
      Smw += pw; d1w += qw; d3w = xor2(d2w - rw, sb[2]); d2w += rw; }
    { v2f pu = xch2<4>(Smu, a32), qu = xch2<4>(d1u, a32),
          ru = xch2<4>(d2u, a32), tu = xch2<4>(d3u, a32);
      v2f pw = xch2<4>(Smw, a32), qw = xch2<4>(d1w, a32),
          rw = xch2<4>(d2w, a32), tw = xch2<4>(d3w, a32);
      Smu += pu; d1u += qu; d2u += ru; d4u = xor2(d3u - tu, sb[3]); d3u += tu;
      Smw += pw; d1w += qw; d2w += rw; d4w = xor2(d3w - tw, sb[3]); d3w += tw; }
    { v2f pu = xch2<2>(Smu, a32), qu = xch2<2>(d1u, a32), ru = xch2<2>(d2u, a32),
          tu = xch2<2>(d3u, a32), wu = xch2<2>(d4u, a32);
      v2f pw = xch2<2>(Smw, a32), qw = xch2<2>(d1w, a32), rw = xch2<2>(d2w, a32),
          tw = xch2<2>(d3w, a32), ww = xch2<2>(d4w, a32);
      Smu += pu; d1u += qu; d2u += ru; d3u += tu;
      d5u = xor2(d4u - wu, sb[4]); d4u += wu;
      Smw += pw; d1w += qw; d2w += rw; d3w += tw;
      d5w = xor2(d4w - ww, sb[4]); d4w += ww; }
    { v2f pu = xch2<1>(Smu, a32), qu = xch2<1>(d1u, a32), ru = xch2<1>(d2u, a32),
          tu = xch2<1>(d3u, a32), wu = xch2<1>(d4u, a32), vu = xch2<1>(d5u, a32);
      v2f pw = xch2<1>(Smw, a32), qw = xch2<1>(d1w, a32), rw = xch2<1>(d2w, a32),
          tw = xch2<1>(d3w, a32), ww = xch2<1>(d4w, a32), vw = xch2<1>(d5w, a32);
      Smu += pu; d1u += qu; d2u += ru; d3u += tu; d4u += wu;
      d6u = xor2(d5u - vu, sb[5]); d5u += vu;
      Smw += pw; d1w += qw; d2w += rw; d3w += tw; d4w += ww;
      d6w = xor2(d5w - vw, sb[5]); d5w += vw; }
    Fvu += xch2<32>(Fvu, a32); Fvw += xch2<32>(Fvw, a32);
    Fvu += xch2<16>(Fvu, a32); Fvw += xch2<16>(Fvw, a32);
    Fvu += xch2<8>(Fvu, a32);  Fvw += xch2<8>(Fvw, a32);
    Fvu += xch2<4>(Fvu, a32);  Fvw += xch2<4>(Fvw, a32);
    Fvu += xch2<2>(Fvu, a32);  Fvw += xch2<2>(Fvw, a32);
    Fvu += xch2<1>(Fvu, a32);  Fvw += xch2<1>(Fvw, a32);
    zu0 = Fvu; zu1 = Smu; zu2 = d1u; zu3 = d2u;
    zu4 = d3u; zu5 = d4u; zu6 = d5u; zu7 = d6u;
    zw0 = Fvw; zw1 = Smw; zw2 = d1w; zw3 = d2w;
    zw4 = d3w; zw5 = d4w; zw6 = d5w; zw7 = d6w;
  }

  // ---- packed projection + stores ----
  const int r0 = 2 * lane;
  const float4* wp = (const float4*)(Wp + r0 * 8);
  float4 w0v = wp[0], w1v = wp[1], w2v = wp[2], w3v = wp[3];
  float2 bpv = ((const float2*)bp)[lane];
  #define PROJ_STORE(P, eA, eB) { \
    v2f o0 = (v2f){bpv.x, bpv.x}; \
    v2f o1 = (v2f){bpv.y, bpv.y}; \
    o0 += z##P##0*w0v.x + z##P##1*w0v.y + z##P##2*w0v.z + z##P##3*w0v.w \
        + z##P##4*w1v.x + z##P##5*w1v.y + z##P##6*w1v.z + z##P##7*w1v.w; \
    o1 += z##P##0*w2v.x + z##P##1*w2v.y + z##P##2*w2v.z + z##P##3*w2v.w \
        + z##P##4*w3v.x + z##P##5*w3v.y + z##P##6*w3v.z + z##P##7*w3v.w; \
    ((float2*)(out + (size_t)(e0 + (eA)) * 128))[lane] = make_float2(o0.x, o1.x); \
    ((float2*)(out + (size_t)(e0 + (eB)) * 128))[lane] = make_float2(o0.y, o1.y); }
  PROJ_STORE(u, 0, 1)
  PROJ_STORE(w, 2, 3)
  #undef PROJ_STORE
}

extern "C" void kernel_launch(void* const* d_in, const int* in_sizes, int n_in,
                              void* d_out, int out_size, void* d_ws, size_t ws_size,
                              hipStream_t stream) {
  const float* x  = (const float*)d_in[0];
  const float* W1 = (const float*)d_in[1];
  const float* b1 = (const float*)d_in[2];
  const float* W2 = (const float*)d_in[3];
  const float* b2 = (const float*)d_in[4];
  const float* W3 = (const float*)d_in[5];
  const float* b3 = (const float*)d_in[6];
  const float* qw = (const float*)d_in[7];
  const float* Wp = (const float*)d_in[8];
  const float* bp = (const float*)d_in[9];
  float* out = (float*)d_out;
  float* Urot = (float*)d_ws;

  const int B = in_sizes[0] / 80;
  const int B4 = B / NE;
  prep_rot_kernel<<<1, 64, 0, stream>>>(qw, Urot);
  const int grid = (B4 + WPB - 1) / WPB;
  qblock_kernel<<<grid, 64 * WPB, 0, stream>>>(x, W1, b1, W2, b2, W3, b3,
                                               Urot, Wp, bp, out, B4);
}